// Round 12
// baseline (3057.160 us; speedup 1.0000x reference)
//
#include <hip/hip_runtime.h>
#include <hip/hip_bf16.h>
#include <math.h>

#define TT   256
#define FF   32
#define CCH  8
#define VV   10000
#define HH   1024
#define EE   256
#define NG   3072        // gate cols r|z|n (original order: g*1024 + j)
#define EOS_ID 2
#define NSTEPS 40
#define CHAIN_BLKS 256   // mt 4 x jb 64
#define CTR_INTS 512
#define VSLICE 157       // v-cols per jb block (64*157 = 10048 >= 10000)

// chain dynamic LDS: B 48*2048 | gp 4*64*52*4 | stb 64*16*2
#define LDS_GP_OFF    98304
#define LDS_STB_OFF   (98304 + 53248)
#define LDS_TOTAL     (98304 + 53248 + 2048)

typedef __attribute__((ext_vector_type(8))) short bf16x8;
typedef __attribute__((ext_vector_type(4))) float f32x4;

__device__ __forceinline__ void gload_lds16(const void* g, void* l) {
    __builtin_amdgcn_global_load_lds((const __attribute__((address_space(1))) void*)g,
                                     (__attribute__((address_space(3))) void*)l,
                                     16, 0, 0);
}

__device__ __forceinline__ float sigmf(float x) { return 1.f / (1.f + __expf(-x)); }

// ---------------------------------------------------------------------------
// prep: decoder ids c_in[t][f], entry-done flags, zero barrier flags
// ---------------------------------------------------------------------------
__global__ __launch_bounds__(256) void prep_kernel(const int* __restrict__ oc,
                                                   int* __restrict__ c_in,
                                                   unsigned char* __restrict__ done,
                                                   int* __restrict__ ctr) {
    int t = threadIdx.x;
    for (int i = t; i < CTR_INTS; i += 256) ctr[i] = 0;
    int c0 = oc[0];
    bool d = (c0 == EOS_ID);
    for (int f = 0; f < FF; ++f) {
        c_in[t * FF + f] = (f == 0) ? c0 : oc[1 + t * FF + f - 1];
        done[t * FF + f] = d ? 1 : 0;
        d = d || (oc[1 + t * FF + f] == EOS_ID);
    }
}

// ---------------------------------------------------------------------------
// h0 (fp32) + A0 = bf16(h0)
// ---------------------------------------------------------------------------
__global__ __launch_bounds__(256) void h0_kernel(const float* __restrict__ tctx,
                                                 const int* __restrict__ sent,
                                                 float* __restrict__ h,
                                                 __hip_bfloat16* __restrict__ A0) {
    int t = blockIdx.x;
    int tid = threadIdx.x;
    __shared__ int xt[CCH];
    if (tid < CCH) xt[tid] = sent[(t * CCH + tid) * 3 + 1];
    __syncthreads();
#pragma unroll
    for (int jj = 0; jj < 4; ++jj) {
        int j = tid + jj * 256;
        float s = 0.f;
#pragma unroll
        for (int c = 0; c < CCH; ++c) s += tctx[(size_t)xt[c] * HH + j];
        float hv = s * 0.125f;
        h[(size_t)t * HH + j] = hv;
        A0[(size_t)t * HH + j] = __float2bfloat16(hv);
    }
}

// ---------------------------------------------------------------------------
// generic fp32 -> bf16
// ---------------------------------------------------------------------------
__global__ __launch_bounds__(256) void f2b_kernel(const float* __restrict__ src,
                                                  __hip_bfloat16* __restrict__ dst) {
    size_t base = ((size_t)blockIdx.x * 256 + threadIdx.x) * 4;
    float4 v = *(const float4*)(src + base);
    dst[base + 0] = __float2bfloat16(v.x);
    dst[base + 1] = __float2bfloat16(v.y);
    dst[base + 2] = __float2bfloat16(v.z);
    dst[base + 3] = __float2bfloat16(v.w);
}

// ---------------------------------------------------------------------------
// Build Bg2 (3072 x 1024 bf16): row n' = jb*48 + g*16 + ji  <-  Whh row
// g*1024 + jb*16 + ji.  jb 0..63, g 0..2, ji 0..15.  grid 3072.
// ---------------------------------------------------------------------------
__global__ __launch_bounds__(256) void build_Bg2(const float* __restrict__ Whh,
                                                 __hip_bfloat16* __restrict__ Bg) {
    int by = blockIdx.x;
    int tid = threadIdx.x;
    int jb = by / 48, rr = by % 48;
    int g = rr >> 4, jj = rr & 15;
    const float* srow = Whh + (size_t)(g * 1024 + jb * 16 + jj) * HH;
    __hip_bfloat16* drow = Bg + (size_t)by * HH;
    float4 v = *(const float4*)(srow + tid * 4);
    drow[tid * 4 + 0] = __float2bfloat16(v.x);
    drow[tid * 4 + 1] = __float2bfloat16(v.y);
    drow[tid * 4 + 2] = __float2bfloat16(v.z);
    drow[tid * 4 + 3] = __float2bfloat16(v.w);
}

// ---------------------------------------------------------------------------
// Pipelined 128x128 MFMA GEMM for x-side gi tables — BF16 OUTPUT.
// MODE 1: enc rows gathered emb_bf[sent char]; MODE 2: dec rows emb_bf[c_in]
// ---------------------------------------------------------------------------
template<int MODE>
__global__ __launch_bounds__(256) void gemm_pipe(const __hip_bfloat16* __restrict__ A, int lda,
                                                 const __hip_bfloat16* __restrict__ B, int ldb,
                                                 __hip_bfloat16* __restrict__ Cb,
                                                 const int* __restrict__ idsrc,
                                                 int NIT) {
    __shared__ __hip_bfloat16 As[4][128 * 32];
    __shared__ __hip_bfloat16 Bs[4][128 * 32];
    __shared__ int sids[128];

    const int tid = threadIdx.x;
    const int n0 = blockIdx.x * 128;
    const int m0 = blockIdx.y * 128;

    if (tid < 128) {
        int row = m0 + tid;
        int t = row & 255;
        int id;
        if (MODE == 1) { int c = row >> 8; id = idsrc[(t * CCH + c) * 3 + 2]; }
        else           { int f = row >> 8; id = idsrc[t * FF + f]; }
        sids[tid] = id;
    }
    __syncthreads();

    const int srow = tid >> 2, skq = tid & 3;
    const int l = tid & 63;
    const int w = tid >> 6;
    const int wr = (w >> 1) * 64, wc = (w & 1) * 64;
    const int fra = ((wr + (l & 15)) << 5) + ((l >> 4) << 3);
    const int frb = ((wc + (l & 15)) << 5) + ((l >> 4) << 3);

    f32x4 acc[4][4];
#pragma unroll
    for (int i = 0; i < 4; ++i)
#pragma unroll
        for (int j = 0; j < 4; ++j) acc[i][j] = (f32x4){0.f, 0.f, 0.f, 0.f};

    auto stage = [&](int slot, int it) {
        const int k0 = it * 32;
        const __hip_bfloat16* ga0 = A + (size_t)sids[srow] * lda + k0 + skq * 8;
        const __hip_bfloat16* ga1 = A + (size_t)sids[64 + srow] * lda + k0 + skq * 8;
        const __hip_bfloat16* gb0 = B + (size_t)(n0 + srow) * ldb + k0 + skq * 8;
        const __hip_bfloat16* gb1 = B + (size_t)(n0 + 64 + srow) * ldb + k0 + skq * 8;
        __hip_bfloat16* lA = &As[slot][tid * 8];
        __hip_bfloat16* lB = &Bs[slot][tid * 8];
        gload_lds16(ga0, lA);
        gload_lds16(ga1, lA + 2048);
        gload_lds16(gb0, lB);
        gload_lds16(gb1, lB + 2048);
    };

    stage(0, 0);
    stage(1, 1);

    for (int it = 0; it < NIT; ++it) {
        if (it + 2 < NIT) stage((it + 2) & 3, it + 2);
        int ahead = NIT - 1 - it; if (ahead > 2) ahead = 2;
        if (ahead >= 2)      asm volatile("s_waitcnt vmcnt(8)" ::: "memory");
        else if (ahead == 1) asm volatile("s_waitcnt vmcnt(4)" ::: "memory");
        else                 asm volatile("s_waitcnt vmcnt(0)" ::: "memory");
        __builtin_amdgcn_s_barrier();
        __builtin_amdgcn_sched_barrier(0);

        const __hip_bfloat16* cA = As[it & 3];
        const __hip_bfloat16* cB = Bs[it & 3];
        bf16x8 af[4], bfv[4];
#pragma unroll
        for (int fm = 0; fm < 4; ++fm) af[fm] = *(const bf16x8*)&cA[fra + fm * 512];
#pragma unroll
        for (int fn = 0; fn < 4; ++fn) bfv[fn] = *(const bf16x8*)&cB[frb + fn * 512];
#pragma unroll
        for (int fm = 0; fm < 4; ++fm)
#pragma unroll
            for (int fn = 0; fn < 4; ++fn)
                acc[fm][fn] = __builtin_amdgcn_mfma_f32_16x16x32_bf16(af[fm], bfv[fn], acc[fm][fn], 0, 0, 0);
    }

    const int colb = wc + (l & 15);
    const int rb   = wr + ((l >> 4) << 2);
#pragma unroll
    for (int fm = 0; fm < 4; ++fm)
#pragma unroll
        for (int fn = 0; fn < 4; ++fn)
#pragma unroll
            for (int q = 0; q < 4; ++q)
                Cb[(size_t)(m0 + rb + fm * 16 + q) * NG + n0 + colb + fn * 16] =
                    __float2bfloat16(acc[fm][fn][q]);
}

// ---------------------------------------------------------------------------
// Persistent chain v9: r11 structure (K-split waves, LDS-persistent B,
// per-mt flag barrier). FUSED variant additionally computes the vocab scores
// inline: at step s>=9 the av registers hold h_state(f=s-9) rows — project
// them against this block's Wout v-slice (jb*157..+156) in 4 col-chunks,
// K-partials reduced via gp LDS, written straight to out. Placed after
// flag-publish so it overlaps other blocks' arrival. Replaces scores_pipe.
// ---------------------------------------------------------------------------
template<bool FUSED>
__global__ __launch_bounds__(256, 1) void chain_kernel(
    __hip_bfloat16* Abuf0, __hip_bfloat16* Abuf1,
    const __hip_bfloat16* __restrict__ Bg_e,
    const __hip_bfloat16* __restrict__ Bg_d,
    const __hip_bfloat16* __restrict__ gi_enc, const __hip_bfloat16* __restrict__ gi_dec,
    const float* __restrict__ ebih, const float* __restrict__ ebhh,
    const float* __restrict__ dbih, const float* __restrict__ dbhh,
    const float* __restrict__ hA,
    __hip_bfloat16* __restrict__ hsb,
    const unsigned char* __restrict__ dflags,
    int* flags,
    const __hip_bfloat16* __restrict__ Woutb,
    const float* __restrict__ bout,
    const int* __restrict__ oc,
    float* __restrict__ outp) {

    extern __shared__ __align__(16) char smem[];
    char* Bs = smem;
    float* gp = (float*)(smem + LDS_GP_OFF);
    __hip_bfloat16* stb = (__hip_bfloat16*)(smem + LDS_STB_OFF);

    const int tid = threadIdx.x;
    const int b = blockIdx.x;
    const int mt = b >> 6, jb = b & 63;
    const int m0 = mt * 64;
    const int jbase = jb * 16;

    const int l = tid & 63, w = tid >> 6;
    const int ji = tid & 15;
    const int rg = tid >> 4;             // 0..15 (epilogue row group)
    const int j = jbase + ji;
    const int lrow = l & 15;             // fragment row lane
    const int lk8  = (l >> 4) << 3;      // fragment k sub-offset (elems)

    const bool zf = FUSED ? (oc[0] == EOS_ID) : false;

    // persistent h (4 t-rows per thread: t = m0 + p*16 + rg)
    float hreg[4];
#pragma unroll
    for (int p = 0; p < 4; ++p)
        hreg[p] = hA[(size_t)(m0 + p * 16 + rg) * HH + j];

    // hoisted biases
    const float e_br = ebih[j] + ebhh[j];
    const float e_bz = ebih[HH + j] + ebhh[HH + j];
    const float e_bi = ebih[2 * HH + j];
    const float e_bh = ebhh[2 * HH + j];
    const float d_br = dbih[j] + dbhh[j];
    const float d_bz = dbih[HH + j] + dbhh[HH + j];
    const float d_bi = dbih[2 * HH + j];
    const float d_bh = dbhh[2 * HH + j];

    auto stageBfull = [&](const __hip_bfloat16* Bp) {
#pragma unroll
        for (int c = 0; c < 24; ++c) {
            int chunk = c * 256 + tid;
            int row = chunk >> 7, q = chunk & 127;
            const char* src = (const char*)(Bp + (size_t)row * HH) + ((q ^ (row & 7)) << 4);
            gload_lds16(src, Bs + chunk * 16);
        }
    };

    auto ldB = [&](int nt, int ks) -> bf16x8 {
        int r = nt * 16 + lrow;
        int g = ks * 4 + (l >> 4);
        return *(const bf16x8*)(Bs + r * 2048 + ((g ^ (r & 7)) << 4));
    };

    // A fragment registers (persist across iterations; asm-written)
    bf16x8 av[8][4];

    // ---- fused score phase: project av (h rows) against Wout v-slice ----
    const int v0 = jb * VSLICE;
    const int vmax = (v0 + VSLICE < VV) ? (v0 + VSLICE) : VV;
    auto score_phase = [&](int f) {
#pragma unroll 1
        for (int ch = 0; ch < 4; ++ch) {
            const int vc = v0 + ch * 48;
            f32x4 sacc[4][3];
#pragma unroll
            for (int m = 0; m < 4; ++m)
#pragma unroll
                for (int nt = 0; nt < 3; ++nt) sacc[m][nt] = (f32x4){0.f, 0.f, 0.f, 0.f};
#pragma unroll
            for (int ksl = 0; ksl < 8; ++ksl) {
                bf16x8 wb0, wb1, wb2;
                { int vv = vc + lrow;      if (vv > VV - 1) vv = VV - 1;
                  wb0 = *(const bf16x8*)(Woutb + (size_t)vv * HH + w * 256 + ksl * 32 + lk8); }
                { int vv = vc + 16 + lrow; if (vv > VV - 1) vv = VV - 1;
                  wb1 = *(const bf16x8*)(Woutb + (size_t)vv * HH + w * 256 + ksl * 32 + lk8); }
                { int vv = vc + 32 + lrow; if (vv > VV - 1) vv = VV - 1;
                  wb2 = *(const bf16x8*)(Woutb + (size_t)vv * HH + w * 256 + ksl * 32 + lk8); }
#pragma unroll
                for (int m = 0; m < 4; ++m) {
                    sacc[m][0] = __builtin_amdgcn_mfma_f32_16x16x32_bf16(av[ksl][m], wb0, sacc[m][0], 0, 0, 0);
                    sacc[m][1] = __builtin_amdgcn_mfma_f32_16x16x32_bf16(av[ksl][m], wb1, sacc[m][1], 0, 0, 0);
                    sacc[m][2] = __builtin_amdgcn_mfma_f32_16x16x32_bf16(av[ksl][m], wb2, sacc[m][2], 0, 0, 0);
                }
            }
            __syncthreads();   // previous chunk's reduce (or epilogue) done with gp
            {
                float* gpw = gp + w * (64 * 52);
                const int rbase = (l >> 4) << 2;
#pragma unroll
                for (int m = 0; m < 4; ++m)
#pragma unroll
                    for (int nt = 0; nt < 3; ++nt)
#pragma unroll
                        for (int q = 0; q < 4; ++q)
                            gpw[(m * 16 + rbase + q) * 52 + nt * 16 + lrow] = sacc[m][nt][q];
            }
            __syncthreads();
            {
                const int r = tid >> 2, q4 = tid & 3;
                const int t = m0 + r;
                float* orow = outp + ((size_t)t * FF + f) * VV;
#pragma unroll
                for (int u = 0; u < 12; ++u) {
                    const int cc = q4 * 12 + u;
                    const int vv = vc + cc;
                    if (vv < vmax) {
                        float sum = gp[0 * 64 * 52 + r * 52 + cc]
                                  + gp[1 * 64 * 52 + r * 52 + cc]
                                  + gp[2 * 64 * 52 + r * 52 + cc]
                                  + gp[3 * 64 * 52 + r * 52 + cc] + bout[vv];
                        __builtin_nontemporal_store(zf ? 0.f : sum, orow + vv);
                    }
                }
            }
        }
    };

    // gi prefetch for s=0 (bf16 -> u16 loads)
    unsigned int gru[4], gzu[4], gnu[4];
    int dfl[4] = {0, 0, 0, 0};
#pragma unroll
    for (int p = 0; p < 4; ++p) {
        const __hip_bfloat16* gb = gi_enc + (size_t)(m0 + p * 16 + rg) * NG + j;
        asm volatile("global_load_ushort %0, %1, off nt" : "=v"(gru[p]) : "v"(gb));
        asm volatile("global_load_ushort %0, %1, off nt" : "=v"(gzu[p]) : "v"(gb + HH));
        asm volatile("global_load_ushort %0, %1, off nt" : "=v"(gnu[p]) : "v"(gb + 2 * HH));
    }

    for (int s = 0; s < NSTEPS; ++s) {
        // ---- entry barrier: wave 0 polls the group's 64 flags ----
        if (s > 0) {
            if (tid < 64) {
                const int* fp = flags + (mt << 6) + l;
                long guard = 0;
                for (;;) {
                    int v;
                    asm volatile("global_load_dword %0, %1, off sc0 sc1" : "=v"(v) : "v"(fp));
                    asm volatile("s_waitcnt vmcnt(0)" ::: "memory");
                    if (__all(v >= s)) break;
                    if (++guard > (1L << 22)) break;
                    __builtin_amdgcn_s_sleep(2);
                }
            }
            __syncthreads();
        }

        // ---- B phase (re)load: once for enc, once for dec ----
        if (s == 0 || s == CCH) {
            stageBfull(((s == 0) ? Bg_e : Bg_d) + (size_t)jb * 48 * HH);
            asm volatile("s_waitcnt vmcnt(0)" ::: "memory");
            __syncthreads();
        }

        const __hip_bfloat16* Ab = (s & 1) ? Abuf1 : Abuf0;
        __hip_bfloat16* An = (s & 1) ? Abuf0 : Abuf1;

        // ---- drain outstanding loads (gi/dfl), then A burst ----
        asm volatile("s_waitcnt vmcnt(0)" ::: "memory");
        const __hip_bfloat16* ap0 = Ab + (size_t)(m0 + 0 * 16 + lrow) * HH + w * 256 + lk8;
        const __hip_bfloat16* ap1 = Ab + (size_t)(m0 + 1 * 16 + lrow) * HH + w * 256 + lk8;
        const __hip_bfloat16* ap2 = Ab + (size_t)(m0 + 2 * 16 + lrow) * HH + w * 256 + lk8;
        const __hip_bfloat16* ap3 = Ab + (size_t)(m0 + 3 * 16 + lrow) * HH + w * 256 + lk8;

#pragma unroll
        for (int ksl = 0; ksl < 8; ++ksl) {
            asm volatile("global_load_dwordx4 %0, %1, off sc0 sc1" : "=v"(av[ksl][0]) : "v"(ap0 + ksl * 32));
            asm volatile("global_load_dwordx4 %0, %1, off sc0 sc1" : "=v"(av[ksl][1]) : "v"(ap1 + ksl * 32));
            asm volatile("global_load_dwordx4 %0, %1, off sc0 sc1" : "=v"(av[ksl][2]) : "v"(ap2 + ksl * 32));
            asm volatile("global_load_dwordx4 %0, %1, off sc0 sc1" : "=v"(av[ksl][3]) : "v"(ap3 + ksl * 32));
        }

        // ---- barrier-free GEMM: 8 K-chunks x 12 MFMA, B via depth-2 reg ring
        f32x4 acc[4][3];
#pragma unroll
        for (int m = 0; m < 4; ++m)
#pragma unroll
            for (int nt = 0; nt < 3; ++nt) acc[m][nt] = (f32x4){0.f, 0.f, 0.f, 0.f};

        const int kbase = w * 8;
        bf16x8 bb[3][3];
#pragma unroll
        for (int nt = 0; nt < 3; ++nt) { bb[0][nt] = ldB(nt, kbase); bb[1][nt] = ldB(nt, kbase + 1); }

#pragma unroll
        for (int ksl = 0; ksl < 8; ++ksl) {
            if (ksl + 2 < 8) {
#pragma unroll
                for (int nt = 0; nt < 3; ++nt) bb[(ksl + 2) % 3][nt] = ldB(nt, kbase + ksl + 2);
            }
            asm volatile("s_waitcnt vmcnt(%0)" :: "i"(28 - 4 * ksl) : "memory");
            __builtin_amdgcn_sched_barrier(0);
#pragma unroll
            for (int m = 0; m < 4; ++m)
#pragma unroll
                for (int nt = 0; nt < 3; ++nt)
                    acc[m][nt] = __builtin_amdgcn_mfma_f32_16x16x32_bf16(av[ksl][m], bb[ksl % 3][nt], acc[m][nt], 0, 0, 0);
        }

        // ---- dump wave K-partials to gp[w][64][52] ----
        {
            float* gpw = gp + w * (64 * 52);
            const int rbase = (l >> 4) << 2;
#pragma unroll
            for (int m = 0; m < 4; ++m)
#pragma unroll
                for (int nt = 0; nt < 3; ++nt)
#pragma unroll
                    for (int q = 0; q < 4; ++q)
                        gpw[(m * 16 + rbase + q) * 52 + nt * 16 + lrow] = acc[m][nt][q];
        }
        __syncthreads();

        // ---- fused GRU epilogue (sum 4 K-partials) ----
        const int f = s - CCH;
        const float br_ = (s < CCH) ? e_br : d_br;
        const float bz_ = (s < CCH) ? e_bz : d_bz;
        const float bi_ = (s < CCH) ? e_bi : d_bi;
        const float bh_ = (s < CCH) ? e_bh : d_bh;
#pragma unroll
        for (int p = 0; p < 4; ++p) {
            const int tr = p * 16 + rg;
            float racc = 0.f, zacc = 0.f, nacc = 0.f;
#pragma unroll
            for (int ww = 0; ww < 4; ++ww) {
                const float* g = gp + ww * (64 * 52) + tr * 52;
                racc += g[ji];
                zacc += g[16 + ji];
                nacc += g[32 + ji];
            }
            float grf = __uint_as_float(gru[p] << 16);
            float gzf = __uint_as_float(gzu[p] << 16);
            float gnf = __uint_as_float(gnu[p] << 16);
            float r = sigmf(grf + br_ + racc);
            float z = sigmf(gzf + bz_ + zacc);
            float n = tanhf(gnf + bi_ + r * (nacc + bh_));
            float hold = hreg[p];
            float hv = (1.f - z) * n + z * hold;
            if (s >= CCH && dfl[p]) hv = hold;
            hreg[p] = hv;
            stb[tr * 16 + ji] = __float2bfloat16(hv);
        }
        __syncthreads();

        // ---- An stores (coalesced), drain, flag ----
        if (s < NSTEPS - 1 || FUSED) {
            if (tid < 128) {
                const int row = tid >> 1, part = tid & 1;
                bf16x8 v = *(const bf16x8*)&stb[row * 16 + part * 8];
                const __hip_bfloat16* ap = An + (size_t)(m0 + row) * HH + jbase + part * 8;
                asm volatile("global_store_dwordx4 %0, %1, off sc0 sc1"
                             :: "v"(ap), "v"(v) : "memory");
            }
            asm volatile("s_waitcnt vmcnt(0)" ::: "memory");   // An visible
            __syncthreads();
            if (tid == 0) {
                int v = s + 1;
                int* fp = flags + (mt << 6) + jb;
                asm volatile("global_store_dword %0, %1, off sc0 sc1"
                             :: "v"(fp), "v"(v) : "memory");
            }
        }
        // hsb store (non-fused path only)
        if (!FUSED) {
            if (s >= CCH && tid < 128) {
                const int row = tid >> 1, part = tid & 1;
                bf16x8 v = *(const bf16x8*)&stb[row * 16 + part * 8];
                bf16x8* hp = (bf16x8*)(hsb + ((size_t)f * TT + m0 + row) * HH + jbase + part * 8);
                __builtin_nontemporal_store(v, hp);
            }
        }
        // fused scores for f = s - 9 (h_state produced at step s-1)
        if (FUSED && s >= CCH + 1) {
            score_phase(s - CCH - 1);
        }
        // prefetch next step's gi/dflags (overlaps other blocks' arrival)
        if (s < NSTEPS - 1) {
            const __hip_bfloat16* gnext = (s + 1 < CCH) ? (gi_enc + (size_t)(s + 1) * TT * NG)
                                                        : (gi_dec + (size_t)(s + 1 - CCH) * TT * NG);
#pragma unroll
            for (int p = 0; p < 4; ++p) {
                const __hip_bfloat16* gb = gnext + (size_t)(m0 + p * 16 + rg) * NG + j;
                asm volatile("global_load_ushort %0, %1, off nt" : "=v"(gru[p]) : "v"(gb));
                asm volatile("global_load_ushort %0, %1, off nt" : "=v"(gzu[p]) : "v"(gb + HH));
                asm volatile("global_load_ushort %0, %1, off nt" : "=v"(gnu[p]) : "v"(gb + 2 * HH));
            }
            if (s + 1 >= CCH) {
                const int fnx = s + 1 - CCH;
#pragma unroll
                for (int p = 0; p < 4; ++p) {
                    const unsigned char* dp = dflags + (size_t)(m0 + p * 16 + rg) * FF + fnx;
                    asm volatile("global_load_ubyte %0, %1, off" : "=v"(dfl[p]) : "v"(dp));
                }
            }
        }
    }

    // ---- fused tail: scores for f = 31 from the final h (flag value 40) ----
    if (FUSED) {
        if (tid < 64) {
            const int* fp = flags + (mt << 6) + l;
            long guard = 0;
            for (;;) {
                int v;
                asm volatile("global_load_dword %0, %1, off sc0 sc1" : "=v"(v) : "v"(fp));
                asm volatile("s_waitcnt vmcnt(0)" ::: "memory");
                if (__all(v >= NSTEPS)) break;
                if (++guard > (1L << 22)) break;
                __builtin_amdgcn_s_sleep(2);
            }
        }
        __syncthreads();
        const __hip_bfloat16* Ab = Abuf0;   // NSTEPS even
        const __hip_bfloat16* ap0 = Ab + (size_t)(m0 + 0 * 16 + lrow) * HH + w * 256 + lk8;
        const __hip_bfloat16* ap1 = Ab + (size_t)(m0 + 1 * 16 + lrow) * HH + w * 256 + lk8;
        const __hip_bfloat16* ap2 = Ab + (size_t)(m0 + 2 * 16 + lrow) * HH + w * 256 + lk8;
        const __hip_bfloat16* ap3 = Ab + (size_t)(m0 + 3 * 16 + lrow) * HH + w * 256 + lk8;
#pragma unroll
        for (int ksl = 0; ksl < 8; ++ksl) {
            asm volatile("global_load_dwordx4 %0, %1, off sc0 sc1" : "=v"(av[ksl][0]) : "v"(ap0 + ksl * 32));
            asm volatile("global_load_dwordx4 %0, %1, off sc0 sc1" : "=v"(av[ksl][1]) : "v"(ap1 + ksl * 32));
            asm volatile("global_load_dwordx4 %0, %1, off sc0 sc1" : "=v"(av[ksl][2]) : "v"(ap2 + ksl * 32));
            asm volatile("global_load_dwordx4 %0, %1, off sc0 sc1" : "=v"(av[ksl][3]) : "v"(ap3 + ksl * 32));
        }
        asm volatile("s_waitcnt vmcnt(0)" ::: "memory");
        score_phase(FF - 1);
    }
}

// ---------------------------------------------------------------------------
// scores (validated r8-r11): pipelined 4-slot ring, counted vmcnt, nt stores.
// Used only when ws is too small for the fused layout.
// ---------------------------------------------------------------------------
__global__ __launch_bounds__(256) void scores_pipe(const __hip_bfloat16* __restrict__ hsb,
                                                   const __hip_bfloat16* __restrict__ Wb,
                                                   const float* __restrict__ bout,
                                                   const int* __restrict__ oc,
                                                   float* __restrict__ out) {
    __shared__ __hip_bfloat16 As[4][128 * 32];
    __shared__ __hip_bfloat16 Bs[4][128 * 32];
    int bid = blockIdx.x;
    int sid = (bid & 7) * 632 + (bid >> 3);      // 5056 = 8*632, bijective
    int bx = sid % 79, by = sid / 79;
    int n0 = bx * 128, m0 = by * 128;

    const int tid = threadIdx.x;
    const int l = tid & 63;
    const int w = tid >> 6;
    const int wr = (w >> 1) * 64, wc = (w & 1) * 64;
    const int srow = tid >> 2, skq = tid & 3;

    f32x4 acc[4][4];
#pragma unroll
    for (int i = 0; i < 4; ++i)
#pragma unroll
        for (int j = 0; j < 4; ++j) acc[i][j] = (f32x4){0.f, 0.f, 0.f, 0.f};

    int br0 = n0 + srow, br1 = n0 + 64 + srow;
    br0 = (br0 > VV - 1) ? VV - 1 : br0;
    br1 = (br1 > VV - 1) ? VV - 1 : br1;
    const __hip_bfloat16* gA0 = hsb + (size_t)(m0 + srow) * HH + skq * 8;
    const __hip_bfloat16* gA1 = hsb + (size_t)(m0 + 64 + srow) * HH + skq * 8;
    const __hip_bfloat16* gB0 = Wb + (size_t)br0 * HH + skq * 8;
    const __hip_bfloat16* gB1 = Wb + (size_t)br1 * HH + skq * 8;
    const int fra = ((wr + (l & 15)) << 5) + ((l >> 4) << 3);
    const int frb = ((wc + (l & 15)) << 5) + ((l >> 4) << 3);

    auto stage = [&](int slot, int it) {
        const int k0 = it * 32;
        __hip_bfloat16* lA = &As[slot][tid * 8];
        __hip_bfloat16* lB = &Bs[slot][tid * 8];
        gload_lds16(gA0 + k0, lA);
        gload_lds16(gA1 + k0, lA + 2048);
        gload_lds16(gB0 + k0, lB);
        gload_lds16(gB1 + k0, lB + 2048);
    };

    stage(0, 0);
    stage(1, 1);

    for (int it = 0; it < 32; ++it) {
        if (it + 2 < 32) stage((it + 2) & 3, it + 2);
        int ahead = 31 - it; if (ahead > 2) ahead = 2;
        if (ahead >= 2)      asm volatile("s_waitcnt vmcnt(8)" ::: "memory");
        else if (ahead == 1) asm volatile("s_waitcnt vmcnt(4)" ::: "memory");
        else                 asm volatile("s_waitcnt vmcnt(0)" ::: "memory");
        __builtin_amdgcn_s_barrier();
        __builtin_amdgcn_sched_barrier(0);

        const __hip_bfloat16* cA = As[it & 3];
        const __hip_bfloat16* cB = Bs[it & 3];
        bf16x8 af[4], bfv[4];
#pragma unroll
        for (int fm = 0; fm < 4; ++fm) af[fm] = *(const bf16x8*)&cA[fra + fm * 512];
#pragma unroll
        for (int fn = 0; fn < 4; ++fn) bfv[fn] = *(const bf16x8*)&cB[frb + fn * 512];
#pragma unroll
        for (int fm = 0; fm < 4; ++fm)
#pragma unroll
            for (int fn = 0; fn < 4; ++fn)
                acc[fm][fn] = __builtin_amdgcn_mfma_f32_16x16x32_bf16(af[fm], bfv[fn], acc[fm][fn], 0, 0, 0);
    }

    const bool zf = (oc[0] == EOS_ID);
    const int colb = wc + (l & 15);
    const int rb   = wr + ((l >> 4) << 2);
#pragma unroll
    for (int fn = 0; fn < 4; ++fn) {
        int v = n0 + colb + fn * 16;
        if (v < VV) {
            float bb = bout[v];
#pragma unroll
            for (int fm = 0; fm < 4; ++fm) {
#pragma unroll
                for (int q = 0; q < 4; ++q) {
                    int m = m0 + rb + fm * 16 + q;
                    int fo = m >> 8, t = m & 255;
                    float val = zf ? 0.f : (acc[fm][fn][q] + bb);
                    __builtin_nontemporal_store(val, &out[(size_t)(t * FF + fo) * VV + v]);
                }
            }
        }
    }
}

// ---------------------------------------------------------------------------
extern "C" void kernel_launch(void* const* d_in, const int* in_sizes, int n_in,
                              void* d_out, int out_size, void* d_ws, size_t ws_size,
                              hipStream_t stream) {
    (void)in_sizes; (void)n_in;

    const float* token_ctx = (const float*)d_in[0];
    const float* emb       = (const float*)d_in[1];
    const float* eWih      = (const float*)d_in[2];
    const float* eWhh      = (const float*)d_in[3];
    const float* ebih      = (const float*)d_in[4];
    const float* ebhh      = (const float*)d_in[5];
    const float* dWih      = (const float*)d_in[6];
    const float* dWhh      = (const float*)d_in[7];
    const float* dbih      = (const float*)d_in[8];
    const float* dbhh      = (const float*)d_in[9];
    const float* Wout      = (const float*)d_in[10];
    const float* bout      = (const float*)d_in[11];
    const int*   sent      = (const int*)d_in[12];
    const int*   ochars    = (const int*)d_in[13];
    float* out = (float*)d_out;

    const bool fused = (ws_size >= (size_t)110 * 1024 * 1024);

    char* w = (char*)d_ws;
    float* hA = (float*)w;                      w += (size_t)TT * HH * 4;
    __hip_bfloat16* Ab0 = (__hip_bfloat16*)w;   w += (size_t)TT * HH * 2;
    __hip_bfloat16* Ab1 = (__hip_bfloat16*)w;   w += (size_t)TT * HH * 2;
    __hip_bfloat16* Woutb = (__hip_bfloat16*)w; w += (size_t)VV * HH * 2;
    int* c_in = (int*)w;                        w += (size_t)TT * FF * 4;
    unsigned char* done = (unsigned char*)w;    w += (size_t)TT * FF;
    w = (char*)(((size_t)w + 255) & ~(size_t)255);
    int* ctr = (int*)w;                         w += (size_t)CTR_INTS * 4;

    __hip_bfloat16 *hsb, *Bg_e, *Bg_d, *gi_enc, *gi_dec, *emb_bf, *Wihb_e, *Wihb_d;
    if (fused) {
        // everything in ws; d_out scratch unused (chain writes scores directly)
        hsb = nullptr;
        gi_enc = (__hip_bfloat16*)w;  w += (size_t)CCH * TT * NG * 2;
        gi_dec = (__hip_bfloat16*)w;  w += (size_t)FF * TT * NG * 2;
        emb_bf = (__hip_bfloat16*)w;  w += (size_t)VV * EE * 2;
        Wihb_e = (__hip_bfloat16*)w;  w += (size_t)NG * EE * 2;
        Wihb_d = (__hip_bfloat16*)w;  w += (size_t)NG * EE * 2;
        Bg_e   = (__hip_bfloat16*)w;  w += (size_t)NG * HH * 2;
        Bg_d   = (__hip_bfloat16*)w;  w += (size_t)NG * HH * 2;
    } else {
        // r11 layout: hsb in ws, rest in the dead d_out tail
        hsb = (__hip_bfloat16*)w;     w += (size_t)FF * TT * HH * 2;
        char* tail = (char*)d_out + (size_t)out_size * 4;
        tail -= (size_t)NG * HH * 2;          Bg_e = (__hip_bfloat16*)tail;
        tail -= (size_t)NG * HH * 2;          Bg_d = (__hip_bfloat16*)tail;
        tail -= (size_t)CCH * TT * NG * 2;    gi_enc = (__hip_bfloat16*)tail;
        tail -= (size_t)FF * TT * NG * 2;     gi_dec = (__hip_bfloat16*)tail;
        tail -= (size_t)VV * EE * 2;          emb_bf = (__hip_bfloat16*)tail;
        tail -= (size_t)NG * EE * 2;          Wihb_e = (__hip_bfloat16*)tail;
        tail -= (size_t)NG * EE * 2;          Wihb_d = (__hip_bfloat16*)tail;
    }

    hipFuncSetAttribute((const void*)chain_kernel<true>,
                        hipFuncAttributeMaxDynamicSharedMemorySize, LDS_TOTAL);
    hipFuncSetAttribute((const void*)chain_kernel<false>,
                        hipFuncAttributeMaxDynamicSharedMemorySize, LDS_TOTAL);

    // ---- prep & conversions ----
    prep_kernel<<<1, 256, 0, stream>>>(ochars, c_in, done, ctr);
    h0_kernel<<<TT, 256, 0, stream>>>(token_ctx, sent, hA, Ab0);
    f2b_kernel<<<(VV * EE) / 4 / 256, 256, 0, stream>>>(emb, emb_bf);
    f2b_kernel<<<(NG * EE) / 4 / 256, 256, 0, stream>>>(eWih, Wihb_e);
    f2b_kernel<<<(NG * EE) / 4 / 256, 256, 0, stream>>>(dWih, Wihb_d);
    f2b_kernel<<<(VV * HH) / 4 / 256, 256, 0, stream>>>(Wout, Woutb);
    build_Bg2<<<NG, 256, 0, stream>>>(eWhh, Bg_e);
    build_Bg2<<<NG, 256, 0, stream>>>(dWhh, Bg_d);

    // ---- x-side tables: gi = emb_bf[ids] @ Wih^T (bf16) ----
    gemm_pipe<1><<<dim3(24, 16), 256, 0, stream>>>(emb_bf, EE, Wihb_e, EE, gi_enc, sent, 8);
    gemm_pipe<2><<<dim3(24, 64), 256, 0, stream>>>(emb_bf, EE, Wihb_d, EE, gi_dec, c_in, 8);

    // ---- persistent recurrent chain (+ fused scores when ws allows) ----
    if (fused) {
        chain_kernel<true><<<CHAIN_BLKS, 256, LDS_TOTAL, stream>>>(
            Ab0, Ab1, Bg_e, Bg_d, gi_enc, gi_dec,
            ebih, ebhh, dbih, dbhh, hA, nullptr, done, ctr,
            Woutb, bout, ochars, out);
    } else {
        chain_kernel<false><<<CHAIN_BLKS, 256, LDS_TOTAL, stream>>>(
            Ab0, Ab1, Bg_e, Bg_d, gi_enc, gi_dec,
            ebih, ebhh, dbih, dbhh, hA, hsb, done, ctr,
            Woutb, bout, ochars, out);
        scores_pipe<<<5056, 256, 0, stream>>>(hsb, Woutb, bout, ochars, out);
    }
}

// Round 13
// 627.768 us; speedup vs baseline: 4.8699x; 4.8699x over previous
//
#include <hip/hip_runtime.h>
#include <hip/hip_bf16.h>
#include <math.h>

#define TT   256
#define FF   32
#define CCH  8
#define VV   10000
#define HH   1024
#define EE   256
#define NG   3072        // gate cols r|z|n (original order: g*1024 + j)
#define EOS_ID 2
#define NSTEPS 40
#define CHAIN_BLKS 256   // mt 4 x jb 64
#define CTR_INTS 512

// chain dynamic LDS: B 48*2048 | gp 4*64*52*4 | stb 64*16*2
#define LDS_GP_OFF    98304
#define LDS_STB_OFF   (98304 + 53248)
#define LDS_TOTAL     (98304 + 53248 + 2048)

// scores256 dynamic LDS: 4 slots x (A 256x32 + B 256x32) bf16 = 4 x 32KB
#define SC_LDS_TOTAL  131072

typedef __attribute__((ext_vector_type(8))) short bf16x8;
typedef __attribute__((ext_vector_type(4))) float f32x4;

__device__ __forceinline__ void gload_lds16(const void* g, void* l) {
    __builtin_amdgcn_global_load_lds((const __attribute__((address_space(1))) void*)g,
                                     (__attribute__((address_space(3))) void*)l,
                                     16, 0, 0);
}

__device__ __forceinline__ float sigmf(float x) { return 1.f / (1.f + __expf(-x)); }

// ---------------------------------------------------------------------------
// prep: decoder ids c_in[t][f], entry-done flags, zero barrier flags
// ---------------------------------------------------------------------------
__global__ __launch_bounds__(256) void prep_kernel(const int* __restrict__ oc,
                                                   int* __restrict__ c_in,
                                                   unsigned char* __restrict__ done,
                                                   int* __restrict__ ctr) {
    int t = threadIdx.x;
    for (int i = t; i < CTR_INTS; i += 256) ctr[i] = 0;
    int c0 = oc[0];
    bool d = (c0 == EOS_ID);
    for (int f = 0; f < FF; ++f) {
        c_in[t * FF + f] = (f == 0) ? c0 : oc[1 + t * FF + f - 1];
        done[t * FF + f] = d ? 1 : 0;
        d = d || (oc[1 + t * FF + f] == EOS_ID);
    }
}

// ---------------------------------------------------------------------------
// h0 (fp32) + A0 = bf16(h0)
// ---------------------------------------------------------------------------
__global__ __launch_bounds__(256) void h0_kernel(const float* __restrict__ tctx,
                                                 const int* __restrict__ sent,
                                                 float* __restrict__ h,
                                                 __hip_bfloat16* __restrict__ A0) {
    int t = blockIdx.x;
    int tid = threadIdx.x;
    __shared__ int xt[CCH];
    if (tid < CCH) xt[tid] = sent[(t * CCH + tid) * 3 + 1];
    __syncthreads();
#pragma unroll
    for (int jj = 0; jj < 4; ++jj) {
        int j = tid + jj * 256;
        float s = 0.f;
#pragma unroll
        for (int c = 0; c < CCH; ++c) s += tctx[(size_t)xt[c] * HH + j];
        float hv = s * 0.125f;
        h[(size_t)t * HH + j] = hv;
        A0[(size_t)t * HH + j] = __float2bfloat16(hv);
    }
}

// ---------------------------------------------------------------------------
// generic fp32 -> bf16
// ---------------------------------------------------------------------------
__global__ __launch_bounds__(256) void f2b_kernel(const float* __restrict__ src,
                                                  __hip_bfloat16* __restrict__ dst) {
    size_t base = ((size_t)blockIdx.x * 256 + threadIdx.x) * 4;
    float4 v = *(const float4*)(src + base);
    dst[base + 0] = __float2bfloat16(v.x);
    dst[base + 1] = __float2bfloat16(v.y);
    dst[base + 2] = __float2bfloat16(v.z);
    dst[base + 3] = __float2bfloat16(v.w);
}

// ---------------------------------------------------------------------------
// Build Bg2 (3072 x 1024 bf16): row n' = jb*48 + g*16 + ji  <-  Whh row
// g*1024 + jb*16 + ji.  jb 0..63, g 0..2, ji 0..15.  grid 3072.
// ---------------------------------------------------------------------------
__global__ __launch_bounds__(256) void build_Bg2(const float* __restrict__ Whh,
                                                 __hip_bfloat16* __restrict__ Bg) {
    int by = blockIdx.x;
    int tid = threadIdx.x;
    int jb = by / 48, rr = by % 48;
    int g = rr >> 4, jj = rr & 15;
    const float* srow = Whh + (size_t)(g * 1024 + jb * 16 + jj) * HH;
    __hip_bfloat16* drow = Bg + (size_t)by * HH;
    float4 v = *(const float4*)(srow + tid * 4);
    drow[tid * 4 + 0] = __float2bfloat16(v.x);
    drow[tid * 4 + 1] = __float2bfloat16(v.y);
    drow[tid * 4 + 2] = __float2bfloat16(v.z);
    drow[tid * 4 + 3] = __float2bfloat16(v.w);
}

// ---------------------------------------------------------------------------
// Pipelined 128x128 MFMA GEMM for x-side gi tables — BF16 OUTPUT.
// MODE 1: enc rows gathered emb_bf[sent char]; MODE 2: dec rows emb_bf[c_in]
// ---------------------------------------------------------------------------
template<int MODE>
__global__ __launch_bounds__(256) void gemm_pipe(const __hip_bfloat16* __restrict__ A, int lda,
                                                 const __hip_bfloat16* __restrict__ B, int ldb,
                                                 __hip_bfloat16* __restrict__ Cb,
                                                 const int* __restrict__ idsrc,
                                                 int NIT) {
    __shared__ __hip_bfloat16 As[4][128 * 32];
    __shared__ __hip_bfloat16 Bs[4][128 * 32];
    __shared__ int sids[128];

    const int tid = threadIdx.x;
    const int n0 = blockIdx.x * 128;
    const int m0 = blockIdx.y * 128;

    if (tid < 128) {
        int row = m0 + tid;
        int t = row & 255;
        int id;
        if (MODE == 1) { int c = row >> 8; id = idsrc[(t * CCH + c) * 3 + 2]; }
        else           { int f = row >> 8; id = idsrc[t * FF + f]; }
        sids[tid] = id;
    }
    __syncthreads();

    const int srow = tid >> 2, skq = tid & 3;
    const int l = tid & 63;
    const int w = tid >> 6;
    const int wr = (w >> 1) * 64, wc = (w & 1) * 64;
    const int fra = ((wr + (l & 15)) << 5) + ((l >> 4) << 3);
    const int frb = ((wc + (l & 15)) << 5) + ((l >> 4) << 3);

    f32x4 acc[4][4];
#pragma unroll
    for (int i = 0; i < 4; ++i)
#pragma unroll
        for (int j = 0; j < 4; ++j) acc[i][j] = (f32x4){0.f, 0.f, 0.f, 0.f};

    auto stage = [&](int slot, int it) {
        const int k0 = it * 32;
        const __hip_bfloat16* ga0 = A + (size_t)sids[srow] * lda + k0 + skq * 8;
        const __hip_bfloat16* ga1 = A + (size_t)sids[64 + srow] * lda + k0 + skq * 8;
        const __hip_bfloat16* gb0 = B + (size_t)(n0 + srow) * ldb + k0 + skq * 8;
        const __hip_bfloat16* gb1 = B + (size_t)(n0 + 64 + srow) * ldb + k0 + skq * 8;
        __hip_bfloat16* lA = &As[slot][tid * 8];
        __hip_bfloat16* lB = &Bs[slot][tid * 8];
        gload_lds16(ga0, lA);
        gload_lds16(ga1, lA + 2048);
        gload_lds16(gb0, lB);
        gload_lds16(gb1, lB + 2048);
    };

    stage(0, 0);
    stage(1, 1);

    for (int it = 0; it < NIT; ++it) {
        if (it + 2 < NIT) stage((it + 2) & 3, it + 2);
        int ahead = NIT - 1 - it; if (ahead > 2) ahead = 2;
        if (ahead >= 2)      asm volatile("s_waitcnt vmcnt(8)" ::: "memory");
        else if (ahead == 1) asm volatile("s_waitcnt vmcnt(4)" ::: "memory");
        else                 asm volatile("s_waitcnt vmcnt(0)" ::: "memory");
        __builtin_amdgcn_s_barrier();
        __builtin_amdgcn_sched_barrier(0);

        const __hip_bfloat16* cA = As[it & 3];
        const __hip_bfloat16* cB = Bs[it & 3];
        bf16x8 af[4], bfv[4];
#pragma unroll
        for (int fm = 0; fm < 4; ++fm) af[fm] = *(const bf16x8*)&cA[fra + fm * 512];
#pragma unroll
        for (int fn = 0; fn < 4; ++fn) bfv[fn] = *(const bf16x8*)&cB[frb + fn * 512];
#pragma unroll
        for (int fm = 0; fm < 4; ++fm)
#pragma unroll
            for (int fn = 0; fn < 4; ++fn)
                acc[fm][fn] = __builtin_amdgcn_mfma_f32_16x16x32_bf16(af[fm], bfv[fn], acc[fm][fn], 0, 0, 0);
    }

    const int colb = wc + (l & 15);
    const int rb   = wr + ((l >> 4) << 2);
#pragma unroll
    for (int fm = 0; fm < 4; ++fm)
#pragma unroll
        for (int fn = 0; fn < 4; ++fn)
#pragma unroll
            for (int q = 0; q < 4; ++q)
                Cb[(size_t)(m0 + rb + fm * 16 + q) * NG + n0 + colb + fn * 16] =
                    __float2bfloat16(acc[fm][fn][q]);
}

// ---------------------------------------------------------------------------
// Persistent chain (r11, validated 341us): K-split waves, LDS-persistent B,
// per-mt flag barrier, bf16 gi tables.
// ---------------------------------------------------------------------------
__global__ __launch_bounds__(256, 1) void chain_kernel(
    __hip_bfloat16* Abuf0, __hip_bfloat16* Abuf1,
    const __hip_bfloat16* __restrict__ Bg_e,
    const __hip_bfloat16* __restrict__ Bg_d,
    const __hip_bfloat16* __restrict__ gi_enc, const __hip_bfloat16* __restrict__ gi_dec,
    const float* __restrict__ ebih, const float* __restrict__ ebhh,
    const float* __restrict__ dbih, const float* __restrict__ dbhh,
    const float* __restrict__ hA,
    __hip_bfloat16* __restrict__ hsb,
    const unsigned char* __restrict__ dflags,
    int* flags) {

    extern __shared__ __align__(16) char smem[];
    char* Bs = smem;
    float* gp = (float*)(smem + LDS_GP_OFF);
    __hip_bfloat16* stb = (__hip_bfloat16*)(smem + LDS_STB_OFF);

    const int tid = threadIdx.x;
    const int b = blockIdx.x;
    const int mt = b >> 6, jb = b & 63;
    const int m0 = mt * 64;
    const int jbase = jb * 16;

    const int l = tid & 63, w = tid >> 6;
    const int ji = tid & 15;
    const int rg = tid >> 4;             // 0..15 (epilogue row group)
    const int j = jbase + ji;
    const int lrow = l & 15;             // fragment row lane
    const int lk8  = (l >> 4) << 3;      // fragment k sub-offset (elems)

    float hreg[4];
#pragma unroll
    for (int p = 0; p < 4; ++p)
        hreg[p] = hA[(size_t)(m0 + p * 16 + rg) * HH + j];

    const float e_br = ebih[j] + ebhh[j];
    const float e_bz = ebih[HH + j] + ebhh[HH + j];
    const float e_bi = ebih[2 * HH + j];
    const float e_bh = ebhh[2 * HH + j];
    const float d_br = dbih[j] + dbhh[j];
    const float d_bz = dbih[HH + j] + dbhh[HH + j];
    const float d_bi = dbih[2 * HH + j];
    const float d_bh = dbhh[2 * HH + j];

    auto stageBfull = [&](const __hip_bfloat16* Bp) {
#pragma unroll
        for (int c = 0; c < 24; ++c) {
            int chunk = c * 256 + tid;
            int row = chunk >> 7, q = chunk & 127;
            const char* src = (const char*)(Bp + (size_t)row * HH) + ((q ^ (row & 7)) << 4);
            gload_lds16(src, Bs + chunk * 16);
        }
    };

    auto ldB = [&](int nt, int ks) -> bf16x8 {
        int r = nt * 16 + lrow;
        int g = ks * 4 + (l >> 4);
        return *(const bf16x8*)(Bs + r * 2048 + ((g ^ (r & 7)) << 4));
    };

    unsigned int gru[4], gzu[4], gnu[4];
    int dfl[4] = {0, 0, 0, 0};
#pragma unroll
    for (int p = 0; p < 4; ++p) {
        const __hip_bfloat16* gb = gi_enc + (size_t)(m0 + p * 16 + rg) * NG + j;
        asm volatile("global_load_ushort %0, %1, off nt" : "=v"(gru[p]) : "v"(gb));
        asm volatile("global_load_ushort %0, %1, off nt" : "=v"(gzu[p]) : "v"(gb + HH));
        asm volatile("global_load_ushort %0, %1, off nt" : "=v"(gnu[p]) : "v"(gb + 2 * HH));
    }

    for (int s = 0; s < NSTEPS; ++s) {
        if (s > 0) {
            if (tid < 64) {
                const int* fp = flags + (mt << 6) + l;
                long guard = 0;
                for (;;) {
                    int v;
                    asm volatile("global_load_dword %0, %1, off sc0 sc1" : "=v"(v) : "v"(fp));
                    asm volatile("s_waitcnt vmcnt(0)" ::: "memory");
                    if (__all(v >= s)) break;
                    if (++guard > (1L << 22)) break;
                    __builtin_amdgcn_s_sleep(2);
                }
            }
            __syncthreads();
        }

        if (s == 0 || s == CCH) {
            stageBfull(((s == 0) ? Bg_e : Bg_d) + (size_t)jb * 48 * HH);
            asm volatile("s_waitcnt vmcnt(0)" ::: "memory");
            __syncthreads();
        }

        const __hip_bfloat16* Ab = (s & 1) ? Abuf1 : Abuf0;
        __hip_bfloat16* An = (s & 1) ? Abuf0 : Abuf1;

        asm volatile("s_waitcnt vmcnt(0)" ::: "memory");
        const __hip_bfloat16* ap0 = Ab + (size_t)(m0 + 0 * 16 + lrow) * HH + w * 256 + lk8;
        const __hip_bfloat16* ap1 = Ab + (size_t)(m0 + 1 * 16 + lrow) * HH + w * 256 + lk8;
        const __hip_bfloat16* ap2 = Ab + (size_t)(m0 + 2 * 16 + lrow) * HH + w * 256 + lk8;
        const __hip_bfloat16* ap3 = Ab + (size_t)(m0 + 3 * 16 + lrow) * HH + w * 256 + lk8;

        bf16x8 av[8][4];
#pragma unroll
        for (int ksl = 0; ksl < 8; ++ksl) {
            asm volatile("global_load_dwordx4 %0, %1, off sc0 sc1" : "=v"(av[ksl][0]) : "v"(ap0 + ksl * 32));
            asm volatile("global_load_dwordx4 %0, %1, off sc0 sc1" : "=v"(av[ksl][1]) : "v"(ap1 + ksl * 32));
            asm volatile("global_load_dwordx4 %0, %1, off sc0 sc1" : "=v"(av[ksl][2]) : "v"(ap2 + ksl * 32));
            asm volatile("global_load_dwordx4 %0, %1, off sc0 sc1" : "=v"(av[ksl][3]) : "v"(ap3 + ksl * 32));
        }

        f32x4 acc[4][3];
#pragma unroll
        for (int m = 0; m < 4; ++m)
#pragma unroll
            for (int nt = 0; nt < 3; ++nt) acc[m][nt] = (f32x4){0.f, 0.f, 0.f, 0.f};

        const int kbase = w * 8;
        bf16x8 bb[3][3];
#pragma unroll
        for (int nt = 0; nt < 3; ++nt) { bb[0][nt] = ldB(nt, kbase); bb[1][nt] = ldB(nt, kbase + 1); }

#pragma unroll
        for (int ksl = 0; ksl < 8; ++ksl) {
            if (ksl + 2 < 8) {
#pragma unroll
                for (int nt = 0; nt < 3; ++nt) bb[(ksl + 2) % 3][nt] = ldB(nt, kbase + ksl + 2);
            }
            asm volatile("s_waitcnt vmcnt(%0)" :: "i"(28 - 4 * ksl) : "memory");
            __builtin_amdgcn_sched_barrier(0);
#pragma unroll
            for (int m = 0; m < 4; ++m)
#pragma unroll
                for (int nt = 0; nt < 3; ++nt)
                    acc[m][nt] = __builtin_amdgcn_mfma_f32_16x16x32_bf16(av[ksl][m], bb[ksl % 3][nt], acc[m][nt], 0, 0, 0);
        }

        {
            float* gpw = gp + w * (64 * 52);
            const int rbase = (l >> 4) << 2;
#pragma unroll
            for (int m = 0; m < 4; ++m)
#pragma unroll
                for (int nt = 0; nt < 3; ++nt)
#pragma unroll
                    for (int q = 0; q < 4; ++q)
                        gpw[(m * 16 + rbase + q) * 52 + nt * 16 + lrow] = acc[m][nt][q];
        }
        __syncthreads();

        const int f = s - CCH;
        const float br_ = (s < CCH) ? e_br : d_br;
        const float bz_ = (s < CCH) ? e_bz : d_bz;
        const float bi_ = (s < CCH) ? e_bi : d_bi;
        const float bh_ = (s < CCH) ? e_bh : d_bh;
#pragma unroll
        for (int p = 0; p < 4; ++p) {
            const int tr = p * 16 + rg;
            float racc = 0.f, zacc = 0.f, nacc = 0.f;
#pragma unroll
            for (int ww = 0; ww < 4; ++ww) {
                const float* g = gp + ww * (64 * 52) + tr * 52;
                racc += g[ji];
                zacc += g[16 + ji];
                nacc += g[32 + ji];
            }
            float grf = __uint_as_float(gru[p] << 16);
            float gzf = __uint_as_float(gzu[p] << 16);
            float gnf = __uint_as_float(gnu[p] << 16);
            float r = sigmf(grf + br_ + racc);
            float z = sigmf(gzf + bz_ + zacc);
            float n = tanhf(gnf + bi_ + r * (nacc + bh_));
            float hold = hreg[p];
            float hv = (1.f - z) * n + z * hold;
            if (s >= CCH && dfl[p]) hv = hold;
            hreg[p] = hv;
            stb[tr * 16 + ji] = __float2bfloat16(hv);
        }
        __syncthreads();

        if (s < NSTEPS - 1) {
            if (tid < 128) {
                const int row = tid >> 1, part = tid & 1;
                bf16x8 v = *(const bf16x8*)&stb[row * 16 + part * 8];
                const __hip_bfloat16* ap = An + (size_t)(m0 + row) * HH + jbase + part * 8;
                asm volatile("global_store_dwordx4 %0, %1, off sc0 sc1"
                             :: "v"(ap), "v"(v) : "memory");
            }
            asm volatile("s_waitcnt vmcnt(0)" ::: "memory");
            __syncthreads();
            if (tid == 0) {
                int v = s + 1;
                int* fp = flags + (mt << 6) + jb;
                asm volatile("global_store_dword %0, %1, off sc0 sc1"
                             :: "v"(fp), "v"(v) : "memory");
            }
        }
        if (s >= CCH && tid < 128) {
            const int row = tid >> 1, part = tid & 1;
            bf16x8 v = *(const bf16x8*)&stb[row * 16 + part * 8];
            bf16x8* hp = (bf16x8*)(hsb + ((size_t)f * TT + m0 + row) * HH + jbase + part * 8);
            __builtin_nontemporal_store(v, hp);
        }
        if (s < NSTEPS - 1) {
            const __hip_bfloat16* gnext = (s + 1 < CCH) ? (gi_enc + (size_t)(s + 1) * TT * NG)
                                                        : (gi_dec + (size_t)(s + 1 - CCH) * TT * NG);
#pragma unroll
            for (int p = 0; p < 4; ++p) {
                const __hip_bfloat16* gb = gnext + (size_t)(m0 + p * 16 + rg) * NG + j;
                asm volatile("global_load_ushort %0, %1, off nt" : "=v"(gru[p]) : "v"(gb));
                asm volatile("global_load_ushort %0, %1, off nt" : "=v"(gzu[p]) : "v"(gb + HH));
                asm volatile("global_load_ushort %0, %1, off nt" : "=v"(gnu[p]) : "v"(gb + 2 * HH));
            }
            if (s + 1 >= CCH) {
                const int fnx = s + 1 - CCH;
#pragma unroll
                for (int p = 0; p < 4; ++p) {
                    const unsigned char* dp = dflags + (size_t)(m0 + p * 16 + rg) * FF + fnx;
                    asm volatile("global_load_ubyte %0, %1, off" : "=v"(dfl[p]) : "v"(dp));
                }
            }
        }
    }
}

// ---------------------------------------------------------------------------
// scores256: 256x256 tile, 512 threads (8 waves, 2M x 4N, each 128x64 out),
// BK=32, 4-slot LDS ring (128KB dynamic), counted vmcnt(8/4/0), XOR-swizzled
// frag reads (both-sides: pre-swizzled global source + swizzled ds_read).
// Halves L2/L3 traffic vs the 128^2 kernel. K-sum order identical -> scores
// bit-identical to scores_pipe.
// ---------------------------------------------------------------------------
__global__ __launch_bounds__(512, 2) void scores256(const __hip_bfloat16* __restrict__ hsb,
                                                    const __hip_bfloat16* __restrict__ Wb,
                                                    const float* __restrict__ bout,
                                                    const int* __restrict__ oc,
                                                    float* __restrict__ out) {
    extern __shared__ __align__(16) char smem[];

    const int bid = blockIdx.x;
    const int sid = (bid & 7) * 160 + (bid >> 3);   // 1280 = 8*160, bijective
    const int bx = sid % 40, by = sid / 40;
    const int n0 = bx * 256, m0 = by * 256;

    const int tid = threadIdx.x;
    const int l = tid & 63;
    const int w = tid >> 6;           // 0..7
    const int wm = w >> 2;            // 0..1  (M half)
    const int wn = w & 3;             // 0..3  (N quarter)
    const int lrow = l & 15;
    const int qg = l >> 4;            // k-group 0..3

    f32x4 acc[8][4];
#pragma unroll
    for (int i = 0; i < 8; ++i)
#pragma unroll
        for (int j = 0; j < 4; ++j) acc[i][j] = (f32x4){0.f, 0.f, 0.f, 0.f};

    // swizzle: qpos = q ^ swz(row), swz(r) = ((r>>1)&3) ^ (r&1)
    auto stage = [&](int slot, int it) {
        const int k0 = it * 32;
        char* sb = smem + slot * 32768;
#pragma unroll
        for (int cc = 0; cc < 2; ++cc) {          // A: 1024 chunks
            int chunk = cc * 512 + tid;
            int row = chunk >> 2, q = chunk & 3;
            int qsrc = q ^ (((row >> 1) & 3) ^ (row & 1));
            const __hip_bfloat16* src = hsb + (size_t)(m0 + row) * HH + k0 + qsrc * 8;
            gload_lds16(src, sb + chunk * 16);
        }
#pragma unroll
        for (int cc = 0; cc < 2; ++cc) {          // B: 1024 chunks
            int chunk = cc * 512 + tid;
            int row = chunk >> 2, q = chunk & 3;
            int br = n0 + row; if (br > VV - 1) br = VV - 1;
            int qsrc = q ^ (((row >> 1) & 3) ^ (row & 1));
            const __hip_bfloat16* src = Wb + (size_t)br * HH + k0 + qsrc * 8;
            gload_lds16(src, sb + 16384 + chunk * 16);
        }
    };

    stage(0, 0);
    stage(1, 1);

    for (int it = 0; it < 32; ++it) {
        if (it + 2 < 32) stage((it + 2) & 3, it + 2);
        int ahead = 31 - it; if (ahead > 2) ahead = 2;
        if (ahead >= 2)      asm volatile("s_waitcnt vmcnt(8)" ::: "memory");
        else if (ahead == 1) asm volatile("s_waitcnt vmcnt(4)" ::: "memory");
        else                 asm volatile("s_waitcnt vmcnt(0)" ::: "memory");
        __builtin_amdgcn_s_barrier();
        __builtin_amdgcn_sched_barrier(0);

        const char* cA = smem + (it & 3) * 32768;
        const char* cB = cA + 16384;
        bf16x8 af[8], bfv[4];
#pragma unroll
        for (int fm = 0; fm < 8; ++fm) {
            int r = wm * 128 + fm * 16 + lrow;
            int qpos = qg ^ (((r >> 1) & 3) ^ (r & 1));
            af[fm] = *(const bf16x8*)(cA + r * 64 + qpos * 16);
        }
#pragma unroll
        for (int fn = 0; fn < 4; ++fn) {
            int r = wn * 64 + fn * 16 + lrow;
            int qpos = qg ^ (((r >> 1) & 3) ^ (r & 1));
            bfv[fn] = *(const bf16x8*)(cB + r * 64 + qpos * 16);
        }
#pragma unroll
        for (int fm = 0; fm < 8; ++fm)
#pragma unroll
            for (int fn = 0; fn < 4; ++fn)
                acc[fm][fn] = __builtin_amdgcn_mfma_f32_16x16x32_bf16(af[fm], bfv[fn], acc[fm][fn], 0, 0, 0);
    }

    const bool zf = (oc[0] == EOS_ID);
    const int colb = wn * 64 + lrow;
    const int rb   = wm * 128 + (qg << 2);
#pragma unroll
    for (int fn = 0; fn < 4; ++fn) {
        int v = n0 + colb + fn * 16;
        if (v < VV) {
            float bb = bout[v];
#pragma unroll
            for (int fm = 0; fm < 8; ++fm) {
#pragma unroll
                for (int q = 0; q < 4; ++q) {
                    int m = m0 + rb + fm * 16 + q;
                    int fo = m >> 8, t = m & 255;
                    float val = zf ? 0.f : (acc[fm][fn][q] + bb);
                    __builtin_nontemporal_store(val, &out[(size_t)(t * FF + fo) * VV + v]);
                }
            }
        }
    }
}

// ---------------------------------------------------------------------------
extern "C" void kernel_launch(void* const* d_in, const int* in_sizes, int n_in,
                              void* d_out, int out_size, void* d_ws, size_t ws_size,
                              hipStream_t stream) {
    (void)in_sizes; (void)n_in; (void)ws_size;

    const float* token_ctx = (const float*)d_in[0];
    const float* emb       = (const float*)d_in[1];
    const float* eWih      = (const float*)d_in[2];
    const float* eWhh      = (const float*)d_in[3];
    const float* ebih      = (const float*)d_in[4];
    const float* ebhh      = (const float*)d_in[5];
    const float* dWih      = (const float*)d_in[6];
    const float* dWhh      = (const float*)d_in[7];
    const float* dbih      = (const float*)d_in[8];
    const float* dbhh      = (const float*)d_in[9];
    const float* Wout      = (const float*)d_in[10];
    const float* bout      = (const float*)d_in[11];
    const int*   sent      = (const int*)d_in[12];
    const int*   ochars    = (const int*)d_in[13];
    float* out = (float*)d_out;

    // ---- ws layout (r11, validated) ----
    char* w = (char*)d_ws;
    float* hA = (float*)w;                      w += (size_t)TT * HH * 4;
    __hip_bfloat16* Ab0 = (__hip_bfloat16*)w;   w += (size_t)TT * HH * 2;
    __hip_bfloat16* Ab1 = (__hip_bfloat16*)w;   w += (size_t)TT * HH * 2;
    __hip_bfloat16* Woutb = (__hip_bfloat16*)w; w += (size_t)VV * HH * 2;
    int* c_in = (int*)w;                        w += (size_t)TT * FF * 4;
    unsigned char* done = (unsigned char*)w;    w += (size_t)TT * FF;
    w = (char*)(((size_t)w + 255) & ~(size_t)255);
    int* ctr = (int*)w;                         w += (size_t)CTR_INTS * 4;
    __hip_bfloat16* hsb = (__hip_bfloat16*)w;   w += (size_t)FF * TT * HH * 2;

    // ---- d_out tail scratch (dead until scores256) ----
    char* tail = (char*)d_out + (size_t)out_size * 4;
    tail -= (size_t)NG * HH * 2;          __hip_bfloat16* Bg_e = (__hip_bfloat16*)tail;
    tail -= (size_t)NG * HH * 2;          __hip_bfloat16* Bg_d = (__hip_bfloat16*)tail;
    tail -= (size_t)CCH * TT * NG * 2;    __hip_bfloat16* gi_enc = (__hip_bfloat16*)tail;
    tail -= (size_t)FF * TT * NG * 2;     __hip_bfloat16* gi_dec = (__hip_bfloat16*)tail;
    tail -= (size_t)VV * EE * 2;          __hip_bfloat16* emb_bf = (__hip_bfloat16*)tail;
    tail -= (size_t)NG * EE * 2;          __hip_bfloat16* Wihb_e = (__hip_bfloat16*)tail;
    tail -= (size_t)NG * EE * 2;          __hip_bfloat16* Wihb_d = (__hip_bfloat16*)tail;

    hipFuncSetAttribute((const void*)chain_kernel,
                        hipFuncAttributeMaxDynamicSharedMemorySize, LDS_TOTAL);
    hipFuncSetAttribute((const void*)scores256,
                        hipFuncAttributeMaxDynamicSharedMemorySize, SC_LDS_TOTAL);

    // ---- prep & conversions ----
    prep_kernel<<<1, 256, 0, stream>>>(ochars, c_in, done, ctr);
    h0_kernel<<<TT, 256, 0, stream>>>(token_ctx, sent, hA, Ab0);
    f2b_kernel<<<(VV * EE) / 4 / 256, 256, 0, stream>>>(emb, emb_bf);
    f2b_kernel<<<(NG * EE) / 4 / 256, 256, 0, stream>>>(eWih, Wihb_e);
    f2b_kernel<<<(NG * EE) / 4 / 256, 256, 0, stream>>>(dWih, Wihb_d);
    f2b_kernel<<<(VV * HH) / 4 / 256, 256, 0, stream>>>(Wout, Woutb);
    build_Bg2<<<NG, 256, 0, stream>>>(eWhh, Bg_e);
    build_Bg2<<<NG, 256, 0, stream>>>(dWhh, Bg_d);

    // ---- x-side tables: gi = emb_bf[ids] @ Wih^T (bf16) ----
    gemm_pipe<1><<<dim3(24, 16), 256, 0, stream>>>(emb_bf, EE, Wihb_e, EE, gi_enc, sent, 8);
    gemm_pipe<2><<<dim3(24, 64), 256, 0, stream>>>(emb_bf, EE, Wihb_d, EE, gi_dec, c_in, 8);

    // ---- persistent recurrent chain (r11, validated) ----
    chain_kernel<<<CHAIN_BLKS, 256, LDS_TOTAL, stream>>>(Ab0, Ab1, Bg_e, Bg_d,
                                                         gi_enc, gi_dec,
                                                         ebih, ebhh, dbih, dbhh,
                                                         hA, hsb, done, ctr);

    // ---- scores: 256^2 tile ----
    scores256<<<1280, 512, SC_LDS_TOTAL, stream>>>(hsb, Woutb, bout, ochars, out);
}

// Round 14
// 601.280 us; speedup vs baseline: 5.0844x; 1.0441x over previous
//
#include <hip/hip_runtime.h>
#include <hip/hip_bf16.h>
#include <math.h>

#define TT   256
#define FF   32
#define CCH  8
#define VV   10000
#define HH   1024
#define EE   256
#define NG   3072        // gate cols r|z|n (original order: g*1024 + j)
#define EOS_ID 2
#define NSTEPS 40
#define CHAIN_BLKS 256   // mt 4 x jb 64
#define CTR_INTS 512

// chain dynamic LDS: B 48*2048 | gp 4*64*52*4 | stb 64*16*2
#define LDS_GP_OFF    98304
#define LDS_STB_OFF   (98304 + 53248)
#define LDS_TOTAL     (98304 + 53248 + 2048)

// scores8p dynamic LDS: 2 buffers x (A 2x16KB + B 2x16KB) = 128KB
#define SC_LDS_TOTAL  131072

typedef __attribute__((ext_vector_type(8))) short bf16x8;
typedef __attribute__((ext_vector_type(4))) float f32x4;

__device__ __forceinline__ void gload_lds16(const void* g, void* l) {
    __builtin_amdgcn_global_load_lds((const __attribute__((address_space(1))) void*)g,
                                     (__attribute__((address_space(3))) void*)l,
                                     16, 0, 0);
}

__device__ __forceinline__ float sigmf(float x) { return 1.f / (1.f + __expf(-x)); }

// ---------------------------------------------------------------------------
// convert_all: fused prework (f2b x4, build_Bg2 x2, prep) — one launch.
// grid 20181 x 256 thr.
// ---------------------------------------------------------------------------
__global__ __launch_bounds__(256) void convert_all(
    const float* __restrict__ emb,  __hip_bfloat16* __restrict__ emb_bf,
    const float* __restrict__ Wihe, __hip_bfloat16* __restrict__ Wihb_e,
    const float* __restrict__ Wihd, __hip_bfloat16* __restrict__ Wihb_d,
    const float* __restrict__ Wout, __hip_bfloat16* __restrict__ Woutb,
    const float* __restrict__ Whhe, __hip_bfloat16* __restrict__ Bg_e,
    const float* __restrict__ Whhd, __hip_bfloat16* __restrict__ Bg_d,
    const int* __restrict__ oc, int* __restrict__ c_in,
    unsigned char* __restrict__ done, int* __restrict__ ctr) {

    int bx = blockIdx.x;
    int tid = threadIdx.x;

    const float* src = nullptr; __hip_bfloat16* dst = nullptr; int lb = 0;
    if (bx < 2500)        { src = emb;  dst = emb_bf;  lb = bx; }
    else if (bx < 3268)   { src = Wihe; dst = Wihb_e; lb = bx - 2500; }
    else if (bx < 4036)   { src = Wihd; dst = Wihb_d; lb = bx - 3268; }
    else if (bx < 14036)  { src = Wout; dst = Woutb;  lb = bx - 4036; }
    if (src) {
        size_t base = ((size_t)lb * 256 + tid) * 4;
        float4 v = *(const float4*)(src + base);
        dst[base + 0] = __float2bfloat16(v.x);
        dst[base + 1] = __float2bfloat16(v.y);
        dst[base + 2] = __float2bfloat16(v.z);
        dst[base + 3] = __float2bfloat16(v.w);
        return;
    }
    if (bx < 20180) {   // build_Bg2 (two ranges)
        const float* Whh = (bx < 17108) ? Whhe : Whhd;
        __hip_bfloat16* Bg = (bx < 17108) ? Bg_e : Bg_d;
        int by = (bx < 17108) ? (bx - 14036) : (bx - 17108);
        int jb = by / 48, rr = by % 48;
        int g = rr >> 4, jj = rr & 15;
        const float* srow = Whh + (size_t)(g * 1024 + jb * 16 + jj) * HH;
        __hip_bfloat16* drow = Bg + (size_t)by * HH;
        float4 v = *(const float4*)(srow + tid * 4);
        drow[tid * 4 + 0] = __float2bfloat16(v.x);
        drow[tid * 4 + 1] = __float2bfloat16(v.y);
        drow[tid * 4 + 2] = __float2bfloat16(v.z);
        drow[tid * 4 + 3] = __float2bfloat16(v.w);
        return;
    }
    // prep (bx == 20180)
    int t = tid;
    for (int i = t; i < CTR_INTS; i += 256) ctr[i] = 0;
    int c0 = oc[0];
    bool d = (c0 == EOS_ID);
    for (int f = 0; f < FF; ++f) {
        c_in[t * FF + f] = (f == 0) ? c0 : oc[1 + t * FF + f - 1];
        done[t * FF + f] = d ? 1 : 0;
        d = d || (oc[1 + t * FF + f] == EOS_ID);
    }
}

// ---------------------------------------------------------------------------
// h0 (fp32) + A0 = bf16(h0)
// ---------------------------------------------------------------------------
__global__ __launch_bounds__(256) void h0_kernel(const float* __restrict__ tctx,
                                                 const int* __restrict__ sent,
                                                 float* __restrict__ h,
                                                 __hip_bfloat16* __restrict__ A0) {
    int t = blockIdx.x;
    int tid = threadIdx.x;
    __shared__ int xt[CCH];
    if (tid < CCH) xt[tid] = sent[(t * CCH + tid) * 3 + 1];
    __syncthreads();
#pragma unroll
    for (int jj = 0; jj < 4; ++jj) {
        int j = tid + jj * 256;
        float s = 0.f;
#pragma unroll
        for (int c = 0; c < CCH; ++c) s += tctx[(size_t)xt[c] * HH + j];
        float hv = s * 0.125f;
        h[(size_t)t * HH + j] = hv;
        A0[(size_t)t * HH + j] = __float2bfloat16(hv);
    }
}

// ---------------------------------------------------------------------------
// gemm_gi: fused enc+dec x-side tables, bf16 out. grid (24, 80):
// by<16 -> enc rows emb_bf[sent char]; else dec rows emb_bf[c_in].
// ---------------------------------------------------------------------------
__global__ __launch_bounds__(256) void gemm_gi(const __hip_bfloat16* __restrict__ A,
                                               const __hip_bfloat16* __restrict__ Be,
                                               const __hip_bfloat16* __restrict__ Bd,
                                               __hip_bfloat16* __restrict__ Ce,
                                               __hip_bfloat16* __restrict__ Cd,
                                               const int* __restrict__ sent,
                                               const int* __restrict__ c_in) {
    __shared__ __hip_bfloat16 As[4][128 * 32];
    __shared__ __hip_bfloat16 Bs[4][128 * 32];
    __shared__ int sids[128];

    const int tid = threadIdx.x;
    const int n0 = blockIdx.x * 128;
    const int byy = blockIdx.y;
    const bool enc = (byy < 16);
    const int m0 = (enc ? byy : byy - 16) * 128;
    const __hip_bfloat16* B = enc ? Be : Bd;
    __hip_bfloat16* Cb = enc ? Ce : Cd;

    if (tid < 128) {
        int row = m0 + tid;
        int t = row & 255;
        int id;
        if (enc) { int c = row >> 8; id = sent[(t * CCH + c) * 3 + 2]; }
        else     { int f = row >> 8; id = c_in[t * FF + f]; }
        sids[tid] = id;
    }
    __syncthreads();

    const int srow = tid >> 2, skq = tid & 3;
    const int l = tid & 63;
    const int w = tid >> 6;
    const int wr = (w >> 1) * 64, wc = (w & 1) * 64;
    const int fra = ((wr + (l & 15)) << 5) + ((l >> 4) << 3);
    const int frb = ((wc + (l & 15)) << 5) + ((l >> 4) << 3);

    f32x4 acc[4][4];
#pragma unroll
    for (int i = 0; i < 4; ++i)
#pragma unroll
        for (int j = 0; j < 4; ++j) acc[i][j] = (f32x4){0.f, 0.f, 0.f, 0.f};

    auto stage = [&](int slot, int it) {
        const int k0 = it * 32;
        const __hip_bfloat16* ga0 = A + (size_t)sids[srow] * EE + k0 + skq * 8;
        const __hip_bfloat16* ga1 = A + (size_t)sids[64 + srow] * EE + k0 + skq * 8;
        const __hip_bfloat16* gb0 = B + (size_t)(n0 + srow) * EE + k0 + skq * 8;
        const __hip_bfloat16* gb1 = B + (size_t)(n0 + 64 + srow) * EE + k0 + skq * 8;
        __hip_bfloat16* lA = &As[slot][tid * 8];
        __hip_bfloat16* lB = &Bs[slot][tid * 8];
        gload_lds16(ga0, lA);
        gload_lds16(ga1, lA + 2048);
        gload_lds16(gb0, lB);
        gload_lds16(gb1, lB + 2048);
    };

    stage(0, 0);
    stage(1, 1);

    for (int it = 0; it < 8; ++it) {
        if (it + 2 < 8) stage((it + 2) & 3, it + 2);
        int ahead = 7 - it; if (ahead > 2) ahead = 2;
        if (ahead >= 2)      asm volatile("s_waitcnt vmcnt(8)" ::: "memory");
        else if (ahead == 1) asm volatile("s_waitcnt vmcnt(4)" ::: "memory");
        else                 asm volatile("s_waitcnt vmcnt(0)" ::: "memory");
        __builtin_amdgcn_s_barrier();
        __builtin_amdgcn_sched_barrier(0);

        const __hip_bfloat16* cA = As[it & 3];
        const __hip_bfloat16* cB = Bs[it & 3];
        bf16x8 af[4], bfv[4];
#pragma unroll
        for (int fm = 0; fm < 4; ++fm) af[fm] = *(const bf16x8*)&cA[fra + fm * 512];
#pragma unroll
        for (int fn = 0; fn < 4; ++fn) bfv[fn] = *(const bf16x8*)&cB[frb + fn * 512];
#pragma unroll
        for (int fm = 0; fm < 4; ++fm)
#pragma unroll
            for (int fn = 0; fn < 4; ++fn)
                acc[fm][fn] = __builtin_amdgcn_mfma_f32_16x16x32_bf16(af[fm], bfv[fn], acc[fm][fn], 0, 0, 0);
    }

    const int colb = wc + (l & 15);
    const int rb   = wr + ((l >> 4) << 2);
#pragma unroll
    for (int fm = 0; fm < 4; ++fm)
#pragma unroll
        for (int fn = 0; fn < 4; ++fn)
#pragma unroll
            for (int q = 0; q < 4; ++q)
                Cb[(size_t)(m0 + rb + fm * 16 + q) * NG + n0 + colb + fn * 16] =
                    __float2bfloat16(acc[fm][fn][q]);
}

// ---------------------------------------------------------------------------
// Persistent chain (r11, validated 341us): K-split waves, LDS-persistent B,
// per-mt flag barrier, bf16 gi tables. UNCHANGED.
// ---------------------------------------------------------------------------
__global__ __launch_bounds__(256, 1) void chain_kernel(
    __hip_bfloat16* Abuf0, __hip_bfloat16* Abuf1,
    const __hip_bfloat16* __restrict__ Bg_e,
    const __hip_bfloat16* __restrict__ Bg_d,
    const __hip_bfloat16* __restrict__ gi_enc, const __hip_bfloat16* __restrict__ gi_dec,
    const float* __restrict__ ebih, const float* __restrict__ ebhh,
    const float* __restrict__ dbih, const float* __restrict__ dbhh,
    const float* __restrict__ hA,
    __hip_bfloat16* __restrict__ hsb,
    const unsigned char* __restrict__ dflags,
    int* flags) {

    extern __shared__ __align__(16) char smem[];
    char* Bs = smem;
    float* gp = (float*)(smem + LDS_GP_OFF);
    __hip_bfloat16* stb = (__hip_bfloat16*)(smem + LDS_STB_OFF);

    const int tid = threadIdx.x;
    const int b = blockIdx.x;
    const int mt = b >> 6, jb = b & 63;
    const int m0 = mt * 64;
    const int jbase = jb * 16;

    const int l = tid & 63, w = tid >> 6;
    const int ji = tid & 15;
    const int rg = tid >> 4;
    const int j = jbase + ji;
    const int lrow = l & 15;
    const int lk8  = (l >> 4) << 3;

    float hreg[4];
#pragma unroll
    for (int p = 0; p < 4; ++p)
        hreg[p] = hA[(size_t)(m0 + p * 16 + rg) * HH + j];

    const float e_br = ebih[j] + ebhh[j];
    const float e_bz = ebih[HH + j] + ebhh[HH + j];
    const float e_bi = ebih[2 * HH + j];
    const float e_bh = ebhh[2 * HH + j];
    const float d_br = dbih[j] + dbhh[j];
    const float d_bz = dbih[HH + j] + dbhh[HH + j];
    const float d_bi = dbih[2 * HH + j];
    const float d_bh = dbhh[2 * HH + j];

    auto stageBfull = [&](const __hip_bfloat16* Bp) {
#pragma unroll
        for (int c = 0; c < 24; ++c) {
            int chunk = c * 256 + tid;
            int row = chunk >> 7, q = chunk & 127;
            const char* src = (const char*)(Bp + (size_t)row * HH) + ((q ^ (row & 7)) << 4);
            gload_lds16(src, Bs + chunk * 16);
        }
    };

    auto ldB = [&](int nt, int ks) -> bf16x8 {
        int r = nt * 16 + lrow;
        int g = ks * 4 + (l >> 4);
        return *(const bf16x8*)(Bs + r * 2048 + ((g ^ (r & 7)) << 4));
    };

    unsigned int gru[4], gzu[4], gnu[4];
    int dfl[4] = {0, 0, 0, 0};
#pragma unroll
    for (int p = 0; p < 4; ++p) {
        const __hip_bfloat16* gb = gi_enc + (size_t)(m0 + p * 16 + rg) * NG + j;
        asm volatile("global_load_ushort %0, %1, off nt" : "=v"(gru[p]) : "v"(gb));
        asm volatile("global_load_ushort %0, %1, off nt" : "=v"(gzu[p]) : "v"(gb + HH));
        asm volatile("global_load_ushort %0, %1, off nt" : "=v"(gnu[p]) : "v"(gb + 2 * HH));
    }

    for (int s = 0; s < NSTEPS; ++s) {
        if (s > 0) {
            if (tid < 64) {
                const int* fp = flags + (mt << 6) + l;
                long guard = 0;
                for (;;) {
                    int v;
                    asm volatile("global_load_dword %0, %1, off sc0 sc1" : "=v"(v) : "v"(fp));
                    asm volatile("s_waitcnt vmcnt(0)" ::: "memory");
                    if (__all(v >= s)) break;
                    if (++guard > (1L << 22)) break;
                    __builtin_amdgcn_s_sleep(2);
                }
            }
            __syncthreads();
        }

        if (s == 0 || s == CCH) {
            stageBfull(((s == 0) ? Bg_e : Bg_d) + (size_t)jb * 48 * HH);
            asm volatile("s_waitcnt vmcnt(0)" ::: "memory");
            __syncthreads();
        }

        const __hip_bfloat16* Ab = (s & 1) ? Abuf1 : Abuf0;
        __hip_bfloat16* An = (s & 1) ? Abuf0 : Abuf1;

        asm volatile("s_waitcnt vmcnt(0)" ::: "memory");
        const __hip_bfloat16* ap0 = Ab + (size_t)(m0 + 0 * 16 + lrow) * HH + w * 256 + lk8;
        const __hip_bfloat16* ap1 = Ab + (size_t)(m0 + 1 * 16 + lrow) * HH + w * 256 + lk8;
        const __hip_bfloat16* ap2 = Ab + (size_t)(m0 + 2 * 16 + lrow) * HH + w * 256 + lk8;
        const __hip_bfloat16* ap3 = Ab + (size_t)(m0 + 3 * 16 + lrow) * HH + w * 256 + lk8;

        bf16x8 av[8][4];
#pragma unroll
        for (int ksl = 0; ksl < 8; ++ksl) {
            asm volatile("global_load_dwordx4 %0, %1, off sc0 sc1" : "=v"(av[ksl][0]) : "v"(ap0 + ksl * 32));
            asm volatile("global_load_dwordx4 %0, %1, off sc0 sc1" : "=v"(av[ksl][1]) : "v"(ap1 + ksl * 32));
            asm volatile("global_load_dwordx4 %0, %1, off sc0 sc1" : "=v"(av[ksl][2]) : "v"(ap2 + ksl * 32));
            asm volatile("global_load_dwordx4 %0, %1, off sc0 sc1" : "=v"(av[ksl][3]) : "v"(ap3 + ksl * 32));
        }

        f32x4 acc[4][3];
#pragma unroll
        for (int m = 0; m < 4; ++m)
#pragma unroll
            for (int nt = 0; nt < 3; ++nt) acc[m][nt] = (f32x4){0.f, 0.f, 0.f, 0.f};

        const int kbase = w * 8;
        bf16x8 bb[3][3];
#pragma unroll
        for (int nt = 0; nt < 3; ++nt) { bb[0][nt] = ldB(nt, kbase); bb[1][nt] = ldB(nt, kbase + 1); }

#pragma unroll
        for (int ksl = 0; ksl < 8; ++ksl) {
            if (ksl + 2 < 8) {
#pragma unroll
                for (int nt = 0; nt < 3; ++nt) bb[(ksl + 2) % 3][nt] = ldB(nt, kbase + ksl + 2);
            }
            asm volatile("s_waitcnt vmcnt(%0)" :: "i"(28 - 4 * ksl) : "memory");
            __builtin_amdgcn_sched_barrier(0);
#pragma unroll
            for (int m = 0; m < 4; ++m)
#pragma unroll
                for (int nt = 0; nt < 3; ++nt)
                    acc[m][nt] = __builtin_amdgcn_mfma_f32_16x16x32_bf16(av[ksl][m], bb[ksl % 3][nt], acc[m][nt], 0, 0, 0);
        }

        {
            float* gpw = gp + w * (64 * 52);
            const int rbase = (l >> 4) << 2;
#pragma unroll
            for (int m = 0; m < 4; ++m)
#pragma unroll
                for (int nt = 0; nt < 3; ++nt)
#pragma unroll
                    for (int q = 0; q < 4; ++q)
                        gpw[(m * 16 + rbase + q) * 52 + nt * 16 + lrow] = acc[m][nt][q];
        }
        __syncthreads();

        const int f = s - CCH;
        const float br_ = (s < CCH) ? e_br : d_br;
        const float bz_ = (s < CCH) ? e_bz : d_bz;
        const float bi_ = (s < CCH) ? e_bi : d_bi;
        const float bh_ = (s < CCH) ? e_bh : d_bh;
#pragma unroll
        for (int p = 0; p < 4; ++p) {
            const int tr = p * 16 + rg;
            float racc = 0.f, zacc = 0.f, nacc = 0.f;
#pragma unroll
            for (int ww = 0; ww < 4; ++ww) {
                const float* g = gp + ww * (64 * 52) + tr * 52;
                racc += g[ji];
                zacc += g[16 + ji];
                nacc += g[32 + ji];
            }
            float grf = __uint_as_float(gru[p] << 16);
            float gzf = __uint_as_float(gzu[p] << 16);
            float gnf = __uint_as_float(gnu[p] << 16);
            float r = sigmf(grf + br_ + racc);
            float z = sigmf(gzf + bz_ + zacc);
            float n = tanhf(gnf + bi_ + r * (nacc + bh_));
            float hold = hreg[p];
            float hv = (1.f - z) * n + z * hold;
            if (s >= CCH && dfl[p]) hv = hold;
            hreg[p] = hv;
            stb[tr * 16 + ji] = __float2bfloat16(hv);
        }
        __syncthreads();

        if (s < NSTEPS - 1) {
            if (tid < 128) {
                const int row = tid >> 1, part = tid & 1;
                bf16x8 v = *(const bf16x8*)&stb[row * 16 + part * 8];
                const __hip_bfloat16* ap = An + (size_t)(m0 + row) * HH + jbase + part * 8;
                asm volatile("global_store_dwordx4 %0, %1, off sc0 sc1"
                             :: "v"(ap), "v"(v) : "memory");
            }
            asm volatile("s_waitcnt vmcnt(0)" ::: "memory");
            __syncthreads();
            if (tid == 0) {
                int v = s + 1;
                int* fp = flags + (mt << 6) + jb;
                asm volatile("global_store_dword %0, %1, off sc0 sc1"
                             :: "v"(fp), "v"(v) : "memory");
            }
        }
        if (s >= CCH && tid < 128) {
            const int row = tid >> 1, part = tid & 1;
            bf16x8 v = *(const bf16x8*)&stb[row * 16 + part * 8];
            bf16x8* hp = (bf16x8*)(hsb + ((size_t)f * TT + m0 + row) * HH + jbase + part * 8);
            __builtin_nontemporal_store(v, hp);
        }
        if (s < NSTEPS - 1) {
            const __hip_bfloat16* gnext = (s + 1 < CCH) ? (gi_enc + (size_t)(s + 1) * TT * NG)
                                                        : (gi_dec + (size_t)(s + 1 - CCH) * TT * NG);
#pragma unroll
            for (int p = 0; p < 4; ++p) {
                const __hip_bfloat16* gb = gnext + (size_t)(m0 + p * 16 + rg) * NG + j;
                asm volatile("global_load_ushort %0, %1, off nt" : "=v"(gru[p]) : "v"(gb));
                asm volatile("global_load_ushort %0, %1, off nt" : "=v"(gzu[p]) : "v"(gb + HH));
                asm volatile("global_load_ushort %0, %1, off nt" : "=v"(gnu[p]) : "v"(gb + 2 * HH));
            }
            if (s + 1 >= CCH) {
                const int fnx = s + 1 - CCH;
#pragma unroll
                for (int p = 0; p < 4; ++p) {
                    const unsigned char* dp = dflags + (size_t)(m0 + p * 16 + rg) * FF + fnx;
                    asm volatile("global_load_ubyte %0, %1, off" : "=v"(dfl[p]) : "v"(dp));
                }
            }
        }
    }
}

// ---------------------------------------------------------------------------
// scores8p: 256x256 tile, 8-phase counted-vmcnt schedule (T3+T4+T5).
// 512 thr = 8 waves (2M x 4N), each 128x64 out. BK=64 (16 K-tiles, 4 phases
// each: {ds-subtile | stage 1 half (2 gloads) | [gate vmcnt(4)] | barrier |
// lgkmcnt(0) | setprio(1) | 16 MFMA | setprio(0) | barrier}).
// Half issue order per kt: Bh0,Bh1,Ah0,Ah1 at lead 6 (half h at phase h-6).
// LDS: 2 buffers x [Ah0|Ah1|Bh0|Bh1] 16KB halves, rows 128B, granule swizzle
// q^(r&7) both-sides. K accumulation order identical to r13 -> bit-identical.
// ---------------------------------------------------------------------------
__global__ __launch_bounds__(512, 2) void scores8p(const __hip_bfloat16* __restrict__ hsb,
                                                   const __hip_bfloat16* __restrict__ Wb,
                                                   const float* __restrict__ bout,
                                                   const int* __restrict__ oc,
                                                   float* __restrict__ out) {
    extern __shared__ __align__(16) char smem[];

    const int bid = blockIdx.x;
    const int sid = (bid & 7) * 160 + (bid >> 3);   // 1280 = 8*160, bijective
    const int bx = sid % 40, by = sid / 40;
    const int n0 = bx * 256, m0 = by * 256;

    const int tid = threadIdx.x;
    const int l = tid & 63;
    const int w = tid >> 6;
    const int wm = w >> 2;            // 0..1
    const int wn = w & 3;             // 0..3
    const int lrow = l & 15;
    const int qg = l >> 4;            // 0..3

    f32x4 acc[8][4];
#pragma unroll
    for (int i = 0; i < 8; ++i)
#pragma unroll
        for (int jj = 0; jj < 4; ++jj) acc[i][jj] = (f32x4){0.f, 0.f, 0.f, 0.f};

    // stage one 16KB half: h -> kt = h>>2, typ = h&3 {0:Bh0 1:Bh1 2:Ah0 3:Ah1}
    auto stage_half = [&](int h) {
        const int kt = h >> 2, typ = h & 3;
        const int k0 = kt * 64;
        char* base = smem + (kt & 1) * 65536 +
                     ((typ < 2) ? (32768 + typ * 16384) : ((typ - 2) * 16384));
#pragma unroll
        for (int c = 0; c < 2; ++c) {
            int g = c * 512 + tid;
            int r = g >> 3, q = g & 7;
            const __hip_bfloat16* src;
            if (typ < 2) {
                int br = n0 + typ * 128 + r; if (br > VV - 1) br = VV - 1;
                src = Wb + (size_t)br * HH + k0 + ((q ^ (r & 7)) << 3);
            } else {
                src = hsb + (size_t)(m0 + (typ - 2) * 128 + r) * HH + k0 + ((q ^ (r & 7)) << 3);
            }
            gload_lds16(src, base + g * 16);
        }
    };

    // prologue: halves 0..5 (kt0 complete + kt1 B-halves)
    for (int h = 0; h < 6; ++h) stage_half(h);
    asm volatile("s_waitcnt vmcnt(4)" ::: "memory");
    __builtin_amdgcn_s_barrier();

    bf16x8 af[4][2], bfv[4][2];

#pragma unroll 1
    for (int kt = 0; kt < 16; ++kt) {
        const char* bufb = smem + (kt & 1) * 65536;
        const char* Abh = bufb + wm * 16384;
        const char* Bbh = bufb + 32768 + (wn >> 1) * 16384;
        const int rbB = (wn & 1) * 64;

        // ---- phase 0: ds A fm0-3 + B fn0-1; MFMA fm0-3 x fn0-1 ----
#pragma unroll
        for (int fm = 0; fm < 4; ++fm) {
            int rr = fm * 16 + lrow;
#pragma unroll
            for (int ks = 0; ks < 2; ++ks)
                af[fm][ks] = *(const bf16x8*)(Abh + rr * 128 + (((ks * 4 + qg) ^ (rr & 7)) << 4));
        }
#pragma unroll
        for (int fn = 0; fn < 2; ++fn) {
            int rr = rbB + fn * 16 + lrow;
#pragma unroll
            for (int ks = 0; ks < 2; ++ks)
                bfv[fn][ks] = *(const bf16x8*)(Bbh + rr * 128 + (((ks * 4 + qg) ^ (rr & 7)) << 4));
        }
        if (4 * kt + 6 < 64) stage_half(4 * kt + 6);
        __builtin_amdgcn_s_barrier();
        asm volatile("s_waitcnt lgkmcnt(0)" ::: "memory");
        __builtin_amdgcn_sched_barrier(0);
        __builtin_amdgcn_s_setprio(1);
#pragma unroll
        for (int fm = 0; fm < 4; ++fm)
#pragma unroll
            for (int fn = 0; fn < 2; ++fn)
#pragma unroll
                for (int ks = 0; ks < 2; ++ks)
                    acc[fm][fn] = __builtin_amdgcn_mfma_f32_16x16x32_bf16(af[fm][ks], bfv[fn][ks], acc[fm][fn], 0, 0, 0);
        __builtin_amdgcn_s_setprio(0);
        __builtin_amdgcn_s_barrier();

        // ---- phase 1: ds B fn2-3; MFMA fm0-3 x fn2-3 ----
#pragma unroll
        for (int fn = 2; fn < 4; ++fn) {
            int rr = rbB + fn * 16 + lrow;
#pragma unroll
            for (int ks = 0; ks < 2; ++ks)
                bfv[fn][ks] = *(const bf16x8*)(Bbh + rr * 128 + (((ks * 4 + qg) ^ (rr & 7)) << 4));
        }
        if (4 * kt + 7 < 64) stage_half(4 * kt + 7);
        __builtin_amdgcn_s_barrier();
        asm volatile("s_waitcnt lgkmcnt(0)" ::: "memory");
        __builtin_amdgcn_sched_barrier(0);
        __builtin_amdgcn_s_setprio(1);
#pragma unroll
        for (int fm = 0; fm < 4; ++fm)
#pragma unroll
            for (int fn = 2; fn < 4; ++fn)
#pragma unroll
                for (int ks = 0; ks < 2; ++ks)
                    acc[fm][fn] = __builtin_amdgcn_mfma_f32_16x16x32_bf16(af[fm][ks], bfv[fn][ks], acc[fm][fn], 0, 0, 0);
        __builtin_amdgcn_s_setprio(0);
        __builtin_amdgcn_s_barrier();

        // ---- phase 2: ds A fm4-7 (B halves now dead); MFMA fm4-7 x fn0-1 ----
#pragma unroll
        for (int fm = 0; fm < 4; ++fm) {
            int rr = (4 + fm) * 16 + lrow;
#pragma unroll
            for (int ks = 0; ks < 2; ++ks)
                af[fm][ks] = *(const bf16x8*)(Abh + rr * 128 + (((ks * 4 + qg) ^ (rr & 7)) << 4));
        }
        if (4 * kt + 8 < 64) stage_half(4 * kt + 8);
        __builtin_amdgcn_s_barrier();
        asm volatile("s_waitcnt lgkmcnt(0)" ::: "memory");
        __builtin_amdgcn_sched_barrier(0);
        __builtin_amdgcn_s_setprio(1);
#pragma unroll
        for (int fm = 0; fm < 4; ++fm)
#pragma unroll
            for (int fn = 0; fn < 2; ++fn)
#pragma unroll
                for (int ks = 0; ks < 2; ++ks)
                    acc[4 + fm][fn] = __builtin_amdgcn_mfma_f32_16x16x32_bf16(af[fm][ks], bfv[fn][ks], acc[4 + fm][fn], 0, 0, 0);
        __builtin_amdgcn_s_setprio(0);
        __builtin_amdgcn_s_barrier();

        // ---- phase 3: MFMA fm4-7 x fn2-3; stage; gate for next kt ----
        if (4 * kt + 9 < 64) stage_half(4 * kt + 9);
        if (kt < 15) {
            if (kt == 14) asm volatile("s_waitcnt vmcnt(0)" ::: "memory");
            else          asm volatile("s_waitcnt vmcnt(4)" ::: "memory");
        }
        __builtin_amdgcn_s_barrier();
        asm volatile("s_waitcnt lgkmcnt(0)" ::: "memory");
        __builtin_amdgcn_sched_barrier(0);
        __builtin_amdgcn_s_setprio(1);
#pragma unroll
        for (int fm = 0; fm < 4; ++fm)
#pragma unroll
            for (int fn = 2; fn < 4; ++fn)
#pragma unroll
                for (int ks = 0; ks < 2; ++ks)
                    acc[4 + fm][fn] = __builtin_amdgcn_mfma_f32_16x16x32_bf16(af[fm][ks], bfv[fn][ks], acc[4 + fm][fn], 0, 0, 0);
        __builtin_amdgcn_s_setprio(0);
        __builtin_amdgcn_s_barrier();
    }

    const bool zf = (oc[0] == EOS_ID);
    const int colb = wn * 64 + lrow;
    const int rb   = wm * 128 + (qg << 2);
#pragma unroll
    for (int fn = 0; fn < 4; ++fn) {
        int v = n0 + colb + fn * 16;
        if (v < VV) {
            float bb = bout[v];
#pragma unroll
            for (int fm = 0; fm < 8; ++fm) {
#pragma unroll
                for (int q = 0; q < 4; ++q) {
                    int m = m0 + rb + fm * 16 + q;
                    int fo = m >> 8, t = m & 255;
                    float val = zf ? 0.f : (acc[fm][fn][q] + bb);
                    __builtin_nontemporal_store(val, &out[(size_t)(t * FF + fo) * VV + v]);
                }
            }
        }
    }
}

// ---------------------------------------------------------------------------
extern "C" void kernel_launch(void* const* d_in, const int* in_sizes, int n_in,
                              void* d_out, int out_size, void* d_ws, size_t ws_size,
                              hipStream_t stream) {
    (void)in_sizes; (void)n_in; (void)ws_size;

    const float* token_ctx = (const float*)d_in[0];
    const float* emb       = (const float*)d_in[1];
    const float* eWih      = (const float*)d_in[2];
    const float* eWhh      = (const float*)d_in[3];
    const float* ebih      = (const float*)d_in[4];
    const float* ebhh      = (const float*)d_in[5];
    const float* dWih      = (const float*)d_in[6];
    const float* dWhh      = (const float*)d_in[7];
    const float* dbih      = (const float*)d_in[8];
    const float* dbhh      = (const float*)d_in[9];
    const float* Wout      = (const float*)d_in[10];
    const float* bout      = (const float*)d_in[11];
    const int*   sent      = (const int*)d_in[12];
    const int*   ochars    = (const int*)d_in[13];
    float* out = (float*)d_out;

    // ---- ws layout (r13, validated) ----
    char* w = (char*)d_ws;
    float* hA = (float*)w;                      w += (size_t)TT * HH * 4;
    __hip_bfloat16* Ab0 = (__hip_bfloat16*)w;   w += (size_t)TT * HH * 2;
    __hip_bfloat16* Ab1 = (__hip_bfloat16*)w;   w += (size_t)TT * HH * 2;
    __hip_bfloat16* Woutb = (__hip_bfloat16*)w; w += (size_t)VV * HH * 2;
    int* c_in = (int*)w;                        w += (size_t)TT * FF * 4;
    unsigned char* done = (unsigned char*)w;    w += (size_t)TT * FF;
    w = (char*)(((size_t)w + 255) & ~(size_t)255);
    int* ctr = (int*)w;                         w += (size_t)CTR_INTS * 4;
    __hip_bfloat16* hsb = (__hip_bfloat16*)w;   w += (size_t)FF * TT * HH * 2;

    // ---- d_out tail scratch (dead until scores8p) ----
    char* tail = (char*)d_out + (size_t)out_size * 4;
    tail -= (size_t)NG * HH * 2;          __hip_bfloat16* Bg_e = (__hip_bfloat16*)tail;
    tail -= (size_t)NG * HH * 2;          __hip_bfloat16* Bg_d = (__hip_bfloat16*)tail;
    tail -= (size_t)CCH * TT * NG * 2;    __hip_bfloat16* gi_enc = (__hip_bfloat16*)tail;
    tail -= (size_t)FF * TT * NG * 2;     __hip_bfloat16* gi_dec = (__hip_bfloat16*)tail;
    tail -= (size_t)VV * EE * 2;          __hip_bfloat16* emb_bf = (__hip_bfloat16*)tail;
    tail -= (size_t)NG * EE * 2;          __hip_bfloat16* Wihb_e = (__hip_bfloat16*)tail;
    tail -= (size_t)NG * EE * 2;          __hip_bfloat16* Wihb_d = (__hip_bfloat16*)tail;

    hipFuncSetAttribute((const void*)chain_kernel,
                        hipFuncAttributeMaxDynamicSharedMemorySize, LDS_TOTAL);
    hipFuncSetAttribute((const void*)scores8p,
                        hipFuncAttributeMaxDynamicSharedMemorySize, SC_LDS_TOTAL);

    // ---- fused prework ----
    convert_all<<<20181, 256, 0, stream>>>(emb, emb_bf, eWih, Wihb_e, dWih, Wihb_d,
                                           Wout, Woutb, eWhh, Bg_e, dWhh, Bg_d,
                                           ochars, c_in, done, ctr);
    h0_kernel<<<TT, 256, 0, stream>>>(token_ctx, sent, hA, Ab0);

    // ---- x-side tables (fused enc+dec) ----
    gemm_gi<<<dim3(24, 80), 256, 0, stream>>>(emb_bf, Wihb_e, Wihb_d,
                                              gi_enc, gi_dec, sent, c_in);

    // ---- persistent recurrent chain (r11, validated) ----
    chain_kernel<<<CHAIN_BLKS, 256, LDS_TOTAL, stream>>>(Ab0, Ab1, Bg_e, Bg_d,
                                                         gi_enc, gi_dec,
                                                         ebih, ebhh, dbih, dbhh,
                                                         hA, hsb, done, ctr);

    // ---- scores: 256^2 8-phase ----
    scores8p<<<1280, 512, SC_LDS_TOTAL, stream>>>(hsb, Woutb, bout, ochars, out);
}